// Round 13
// baseline (2529.604 us; speedup 1.0000x reference)
//
#include <hip/hip_runtime.h>
#include <math.h>

typedef __attribute__((ext_vector_type(8))) __bf16 bf16x8;
typedef __attribute__((ext_vector_type(4))) float f32x4;

constexpr int H = 1024, T = 64, NB = 256, TWOH = 2048, THREEH = 3072;
constexpr long long OFF_Q  = 33554432LL;
constexpr long long OFF_HX = 67108864LL;
constexpr int LA = 6;      // filler lookahead (ring of 8 slices)

// Wbf row offsets (rows of 1024 bf16, byte stride 2048)
constexpr int R_PWH = 0, R_PWQ = 2048, R_QWF = 4096, R_QWC = 6144,
              R_FWIH = 8192, R_FWHH = 11264, R_HWIH = 14336, R_HWHH = 17408;

#define LD4(p) (*reinterpret_cast<const float4*>(p))

__device__ __forceinline__ float sigf(float x) { return 1.0f / (1.0f + expf(-x)); }

__device__ __forceinline__ void gload16(const void* g, void* l) {
    __builtin_amdgcn_global_load_lds(
        (const __attribute__((address_space(1))) uint32_t*)g,
        (__attribute__((address_space(3))) uint32_t*)l, 16, 0, 0);
}

__device__ __forceinline__ void st_bf_swz(__bf16* base, int n, int k, float v) {
    base[(size_t)n * 1024 + (((k >> 3) ^ (n & 7)) << 3) + (k & 7)] = (__bf16)v;
}

#define FRAGOFF(rloc, gl) (((rloc) << 7) + ((((gl)) ^ ((rloc) & 7)) << 4))

// stage RT rows x 64 k with a 256-thread half (tid 0..255)
template<int RT>
__device__ __forceinline__ void stage_tile(const char* g, char* l, int kb, int tid) {
    #pragma unroll
    for (int i = 0; i < RT / 32; ++i) {
        const int L = i * 4096 + tid * 16;
        gload16(g + (size_t)(L >> 7) * 2048 + (size_t)kb * 128 + (L & 127), l + L);
    }
}

// stage RT rows x 64 k with all 512 threads
template<int RT>
__device__ __forceinline__ void stage512(const char* g, char* l, int kb, int tid) {
    #pragma unroll
    for (int i = 0; i < RT / 64; ++i) {
        const int L = i * 8192 + tid * 16;
        gload16(g + (size_t)(L >> 7) * 2048 + (size_t)kb * 128 + (L & 127), l + L);
    }
}

// ---------------------------------------------------------------- 64x256 GEMM core
// 512 threads = 8 waves (2 row x 4 col). 3-deep; 5 loads/wave/stage -> vmcnt 10/5/0.
// sA: 3 x 8KB = 24KB; sB: 3 x 32KB = 96KB. 32 s_barriers total.
__device__ __forceinline__ void mm256(
    int tid, char* sA, char* sB,
    const char* A, const char* B,
    f32x4 (&acc)[2][4])
{
    const int lane = tid & 63, w = tid >> 6;
    const int l15 = lane & 15, lg = lane >> 4;
    const int wr = w >> 2, wc = w & 3;
    int aoff[2][2], boff[4][2];
    #pragma unroll
    for (int fr = 0; fr < 2; ++fr)
        #pragma unroll
        for (int kk = 0; kk < 2; ++kk)
            aoff[fr][kk] = FRAGOFF(wr * 32 + fr * 16 + l15, kk * 4 + lg);
    #pragma unroll
    for (int fc = 0; fc < 4; ++fc)
        #pragma unroll
        for (int kk = 0; kk < 2; ++kk)
            boff[fc][kk] = FRAGOFF(wc * 64 + fc * 16 + l15, kk * 4 + lg);

    stage512<64>(A, sA, 0, tid);
    stage512<256>(B, sB, 0, tid);
    stage512<64>(A, sA + 8192, 1, tid);
    stage512<256>(B, sB + 32768, 1, tid);
    for (int kb = 0; kb < 16; ++kb) {
        const int kn = kb + 2;
        if (kn < 16) {
            const int bo = kn % 3;
            stage512<64>(A, sA + bo * 8192, kn, tid);
            stage512<256>(B, sB + bo * 32768, kn, tid);
            asm volatile("s_waitcnt vmcnt(10)" ::: "memory");
        } else if (kb + 1 < 16) {
            asm volatile("s_waitcnt vmcnt(5)" ::: "memory");
        } else {
            asm volatile("s_waitcnt vmcnt(0)" ::: "memory");
        }
        __builtin_amdgcn_s_barrier();
        __builtin_amdgcn_sched_barrier(0);
        const int bc = kb % 3;
        char* Ab = sA + bc * 8192;
        char* Bb = sB + bc * 32768;
        bf16x8 af[2][2], bv[4][2];
        #pragma unroll
        for (int fr = 0; fr < 2; ++fr)
            #pragma unroll
            for (int kk = 0; kk < 2; ++kk)
                af[fr][kk] = *reinterpret_cast<const bf16x8*>(Ab + aoff[fr][kk]);
        #pragma unroll
        for (int fc = 0; fc < 4; ++fc)
            #pragma unroll
            for (int kk = 0; kk < 2; ++kk)
                bv[fc][kk] = *reinterpret_cast<const bf16x8*>(Bb + boff[fc][kk]);
        __builtin_amdgcn_s_setprio(1);
        #pragma unroll
        for (int kk = 0; kk < 2; ++kk)
            #pragma unroll
            for (int fr = 0; fr < 2; ++fr)
                #pragma unroll
                for (int fc = 0; fc < 4; ++fc)
                    acc[fr][fc] = __builtin_amdgcn_mfma_f32_16x16x32_bf16(
                        af[fr][kk], bv[fc][kk], acc[fr][fc], 0, 0, 0);
        __builtin_amdgcn_s_setprio(0);
        __builtin_amdgcn_s_barrier();
        __builtin_amdgcn_sched_barrier(0);
    }
}

// ---------------------------------------------------------------- 32x64 1-seg 3-gate core
// 256-thread half; barriers sync the full 512 workgroup (both halves run 32 barriers).
// sA: 2 x 4KB, sB: 2 x 24KB (56KB per half).
__device__ __forceinline__ void mm32g1(
    int tid, char* sA, char* sB,
    const char* A, const char* Bg,
    f32x4 (&aR)[2], f32x4 (&aZ)[2], f32x4 (&aN)[2])
{
    const int lane = tid & 63, w = tid >> 6;
    const int l15 = lane & 15, lg = lane >> 4;
    const int wr = w >> 1, wc = w & 1;
    int aoff[2], boff[2][2];
    #pragma unroll
    for (int kk = 0; kk < 2; ++kk)
        aoff[kk] = FRAGOFF(wr * 16 + l15, kk * 4 + lg);
    #pragma unroll
    for (int fc = 0; fc < 2; ++fc)
        #pragma unroll
        for (int kk = 0; kk < 2; ++kk)
            boff[fc][kk] = FRAGOFF(wc * 32 + fc * 16 + l15, kk * 4 + lg);

    auto stg = [&](int buf, int kb) {
        stage_tile<32>(A, sA + buf * 4096, kb, tid);
        #pragma unroll
        for (int g = 0; g < 3; ++g)
            stage_tile<64>(Bg + (size_t)g * 2097152, sB + buf * 24576 + g * 8192, kb, tid);
    };
    stg(0, 0);
    for (int kb = 0; kb < 16; ++kb) {
        if (kb + 1 < 16) {
            stg((kb + 1) & 1, kb + 1);
            asm volatile("s_waitcnt vmcnt(7)" ::: "memory");
        } else {
            asm volatile("s_waitcnt vmcnt(0)" ::: "memory");
        }
        __builtin_amdgcn_s_barrier();
        __builtin_amdgcn_sched_barrier(0);
        char* Ab = sA + (kb & 1) * 4096;
        char* Bb = sB + (kb & 1) * 24576;
        bf16x8 af[2];
        #pragma unroll
        for (int kk = 0; kk < 2; ++kk)
            af[kk] = *reinterpret_cast<const bf16x8*>(Ab + aoff[kk]);
        bf16x8 bvr[2][2], bvz[2][2], bvn[2][2];
        #pragma unroll
        for (int fc = 0; fc < 2; ++fc)
            #pragma unroll
            for (int kk = 0; kk < 2; ++kk) {
                bvr[fc][kk] = *reinterpret_cast<const bf16x8*>(Bb + boff[fc][kk]);
                bvz[fc][kk] = *reinterpret_cast<const bf16x8*>(Bb + 8192 + boff[fc][kk]);
                bvn[fc][kk] = *reinterpret_cast<const bf16x8*>(Bb + 16384 + boff[fc][kk]);
            }
        __builtin_amdgcn_s_setprio(1);
        #pragma unroll
        for (int kk = 0; kk < 2; ++kk)
            #pragma unroll
            for (int fc = 0; fc < 2; ++fc) {
                aR[fc] = __builtin_amdgcn_mfma_f32_16x16x32_bf16(af[kk], bvr[fc][kk], aR[fc], 0, 0, 0);
                aZ[fc] = __builtin_amdgcn_mfma_f32_16x16x32_bf16(af[kk], bvz[fc][kk], aZ[fc], 0, 0, 0);
                aN[fc] = __builtin_amdgcn_mfma_f32_16x16x32_bf16(af[kk], bvn[fc][kk], aN[fc], 0, 0, 0);
            }
        __builtin_amdgcn_s_setprio(0);
        __builtin_amdgcn_s_barrier();
        __builtin_amdgcn_sched_barrier(0);
    }
}

// ---------------------------------------------------------------- mono bodies (512 thr)
// xq: out_q[slice] = c@qWc^T + a@qWa^T. 32 tasks/slice (4 rows x 8 cols).
__device__ __forceinline__ void do_xq(int slice, int i, int tid, char* sA, char* sB,
    const char* cbfB, const char* Wb, const float* act, const float* qW, float* out,
    bool wr_en)
{
    const int lane = tid & 63, w = tid >> 6;
    const int l15 = lane & 15, lg = lane >> 4;
    const int wr = w >> 2, wc = w & 3;
    const int row0 = (i >> 3) * 64, col0 = (i & 7) * 256;
    const size_t grow0 = (size_t)slice * NB + row0;
    f32x4 acc[2][4] = {};
    mm256(tid, sA, sB, cbfB + grow0 * 2048, Wb + (size_t)(R_QWC + col0) * 2048, acc);
    if (!wr_en) return;
    #pragma unroll
    for (int fc = 0; fc < 4; ++fc) {
        const int gc = col0 + wc * 64 + fc * 16 + l15;
        const float* wp = qW + (size_t)gc * 2056 + 2048;
        float4 x0 = LD4(wp), x1 = LD4(wp + 4);
        #pragma unroll
        for (int fr = 0; fr < 2; ++fr)
            #pragma unroll
            for (int j = 0; j < 4; ++j) {
                const size_t n = grow0 + wr * 32 + fr * 16 + lg * 4 + j;
                const float* ar = act + n * 8;
                float4 a0 = LD4(ar), a1 = LD4(ar + 4);
                float dot = a0.x * x0.x + a0.y * x0.y + a0.z * x0.z + a0.w * x0.w
                          + a1.x * x1.x + a1.y * x1.y + a1.z * x1.z + a1.w * x1.w;
                out[OFF_Q + n * TWOH + gc] = acc[fr][fc][j] + dot;
            }
    }
}

// Gf: Gfb[slot] = c_t@fWih^T. 48 tasks/slice (4 rows x 12 cols).
__device__ __forceinline__ void do_gf(int slice, int i, int tid, char* sA, char* sB,
    const char* cbfB, const char* Wb, __bf16* Gfb, bool wr_en)
{
    const int lane = tid & 63, w = tid >> 6;
    const int l15 = lane & 15, lg = lane >> 4;
    const int wr = w >> 2, wc = w & 3;
    const int row0 = (i / 12) * 64, col0 = (i % 12) * 256;
    f32x4 acc[2][4] = {};
    mm256(tid, sA, sB, cbfB + ((size_t)slice * NB + row0) * 2048,
          Wb + (size_t)(R_FWIH + col0) * 2048, acc);
    if (!wr_en) return;
    __bf16* gdst = Gfb + (size_t)(slice & 7) * NB * THREEH;
    #pragma unroll
    for (int fc = 0; fc < 4; ++fc) {
        const int gc = col0 + wc * 64 + fc * 16 + l15;
        #pragma unroll
        for (int fr = 0; fr < 2; ++fr)
            #pragma unroll
            for (int j = 0; j < 4; ++j) {
                const int n = row0 + wr * 32 + fr * 16 + lg * 4 + j;
                gdst[(size_t)n * THREEH + gc] = (__bf16)acc[fr][fc][j];
            }
    }
}

// Pq partial: out_p[tt] = qmu(tt)@pWq^T + m*a@pWa^T + pb. 32 tasks.
__device__ __forceinline__ void do_pq(int tt, int i, int tid, char* sA, char* sB,
    const __bf16* qmu_t, const char* Wb, const float* masks, const float* act,
    const float* pW, const float* pb, float* out, bool wr_en)
{
    const int lane = tid & 63, w = tid >> 6;
    const int l15 = lane & 15, lg = lane >> 4;
    const int wr = w >> 2, wc = w & 3;
    const int row0 = (i >> 3) * 64, col0 = (i & 7) * 256;
    f32x4 acc[2][4] = {};
    mm256(tid, sA, sB, (const char*)qmu_t + (size_t)row0 * 2048,
          Wb + (size_t)(R_PWQ + col0) * 2048, acc);
    if (!wr_en) return;
    const float* mrow = masks + (size_t)tt * NB;
    float* ob = out + (size_t)tt * NB * TWOH;
    #pragma unroll
    for (int fc = 0; fc < 4; ++fc) {
        const int gc = col0 + wc * 64 + fc * 16 + l15;
        const float* wp = pW + (size_t)gc * 2056 + 2048;
        float4 x0 = LD4(wp), x1 = LD4(wp + 4);
        const float bb = pb[gc];
        #pragma unroll
        for (int fr = 0; fr < 2; ++fr)
            #pragma unroll
            for (int j = 0; j < 4; ++j) {
                const int n = row0 + wr * 32 + fr * 16 + lg * 4 + j;
                const float* ar = act + ((size_t)tt * NB + n) * 8;
                float4 a0 = LD4(ar), a1 = LD4(ar + 4);
                float dot = a0.x * x0.x + a0.y * x0.y + a0.z * x0.z + a0.w * x0.w
                          + a1.x * x1.x + a1.y * x1.y + a1.z * x1.z + a1.w * x1.w;
                ob[(size_t)n * TWOH + gc] = acc[fr][fc][j] + mrow[n] * dot + bb;
            }
    }
}

// ---------------------------------------------------------------- prepass kernels
__global__ __launch_bounds__(256) void wcvt_k(
    const float* __restrict__ pW, const float* __restrict__ qW,
    const float* __restrict__ fWih, const float* __restrict__ fWhh,
    const float* __restrict__ hWih, const float* __restrict__ hWhh,
    __bf16* __restrict__ Wbf)
{
    const long i = (long)blockIdx.x * 256 + threadIdx.x;
    const int row = (int)(i >> 7);
    const int G   = (int)i & 127;
    const float* src; int stride; int koff = 0; int r;
    if (row < 2048)       { src = pW;   stride = 2056; koff = 0;    r = row; }
    else if (row < 4096)  { src = pW;   stride = 2056; koff = 1024; r = row - 2048; }
    else if (row < 6144)  { src = qW;   stride = 2056; koff = 0;    r = row - 4096; }
    else if (row < 8192)  { src = qW;   stride = 2056; koff = 1024; r = row - 6144; }
    else if (row < 11264) { src = fWih; stride = 1024; r = row - 8192; }
    else if (row < 14336) { src = fWhh; stride = 1024; r = row - 11264; }
    else if (row < 17408) { src = hWih; stride = 1024; r = row - 14336; }
    else                  { src = hWhh; stride = 1024; r = row - 17408; }
    const float* p = src + (long)r * stride + koff + G * 8;
    float4 a = LD4(p), b = LD4(p + 4);
    bf16x8 v;
    v[0] = (__bf16)a.x; v[1] = (__bf16)a.y; v[2] = (__bf16)a.z; v[3] = (__bf16)a.w;
    v[4] = (__bf16)b.x; v[5] = (__bf16)b.y; v[6] = (__bf16)b.z; v[7] = (__bf16)b.w;
    *reinterpret_cast<bf16x8*>(Wbf + (size_t)row * 1024 + ((G ^ (row & 7)) << 3)) = v;
}

__global__ __launch_bounds__(256) void ccvt_k(const float* __restrict__ c,
                                              __bf16* __restrict__ cbf) {
    const long i = (long)blockIdx.x * 256 + threadIdx.x;
    const int row = (int)(i >> 7);
    const int G   = (int)i & 127;
    const float* p = c + (size_t)row * 1024 + G * 8;
    float4 a = LD4(p), b = LD4(p + 4);
    bf16x8 v;
    v[0] = (__bf16)a.x; v[1] = (__bf16)a.y; v[2] = (__bf16)a.z; v[3] = (__bf16)a.w;
    v[4] = (__bf16)b.x; v[5] = (__bf16)b.y; v[6] = (__bf16)b.z; v[7] = (__bf16)b.w;
    *reinterpret_cast<bf16x8*>(cbf + (size_t)row * 1024 + ((G ^ (row & 7)) << 3)) = v;
}

__global__ __launch_bounds__(256) void init2_k(
    const float* __restrict__ hxs, const float* __restrict__ masks,
    float* __restrict__ fst0, float* __restrict__ hst0,
    __bf16* __restrict__ fbm0, __bf16* __restrict__ hbm0, __bf16* __restrict__ qmub0)
{
    const int idx = blockIdx.x * 256 + threadIdx.x;
    const int arr = idx >> 15;
    const int g   = idx & 32767;
    const int n   = g >> 7;
    const int G   = g & 127;
    const float m0 = masks[n];
    const float* p = hxs + (size_t)n * THREEH + arr * 1024 + G * 8;
    float4 a = LD4(p), b = LD4(p + 4);
    __bf16* dstB = arr == 0 ? fbm0 : (arr == 1 ? hbm0 : qmub0);
    bf16x8 v;
    v[0] = (__bf16)(a.x * m0); v[1] = (__bf16)(a.y * m0);
    v[2] = (__bf16)(a.z * m0); v[3] = (__bf16)(a.w * m0);
    v[4] = (__bf16)(b.x * m0); v[5] = (__bf16)(b.y * m0);
    v[6] = (__bf16)(b.z * m0); v[7] = (__bf16)(b.w * m0);
    *reinterpret_cast<bf16x8*>(dstB + (size_t)n * 1024 + ((G ^ (n & 7)) << 3)) = v;
    if (arr < 2) {
        float* dstF = arr == 0 ? fst0 : hst0;
        *reinterpret_cast<float4*>(dstF + (size_t)n * 1024 + G * 8) = a;
        *reinterpret_cast<float4*>(dstF + (size_t)n * 1024 + G * 8 + 4) = b;
    }
}

// slices 0..LA-1 of xq (32) + Gf (48) = 80/slice, plus Pq(0) (32)
__global__ __launch_bounds__(512) void pre_k(
    const char* __restrict__ cbfB, const char* __restrict__ Wb,
    const float* __restrict__ act, const float* __restrict__ qW,
    const __bf16* __restrict__ qmb0, const float* __restrict__ masks,
    const float* __restrict__ pW, const float* __restrict__ pb,
    __bf16* __restrict__ Gfb, float* __restrict__ out)
{
    __shared__ char smem[122880];
    const int tid = threadIdx.x;
    const int b = blockIdx.x;
    if (b < LA * 80) {
        const int s = b / 80;
        const int i = b % 80;
        if (i < 32) do_xq(s, i, tid, smem, smem + 24576, cbfB, Wb, act, qW, out, true);
        else        do_gf(s, i - 32, tid, smem, smem + 24576, cbfB, Wb, Gfb, true);
    } else {
        do_pq(0, b - LA * 80, tid, smem, smem + 24576, qmb0, Wb, masks, act, pW, pb, out, true);
    }
}

// ---------------------------------------------------------------- per-step K1 (176 blocks x 512)
// [0,32) Pfinal | [32,64) Q | [64,112) Shh | [112,176) f-GRU pairs
__global__ __launch_bounds__(512) void k1_k(
    int t,
    const __bf16* __restrict__ hbm, const __bf16* __restrict__ fbm,
    __bf16* __restrict__ qmubN,
    const float* __restrict__ masks, const float* __restrict__ act,
    const float* __restrict__ qb, const float* __restrict__ qW,
    const char* __restrict__ Wb,
    __bf16* __restrict__ pmub, float* __restrict__ Shh,
    const __bf16* __restrict__ Gfb,
    const float* __restrict__ fbih, const float* __restrict__ fbhh,
    const float* __restrict__ fstF, float* __restrict__ fstN, __bf16* __restrict__ fbmN,
    float* __restrict__ out)
{
    __shared__ char smem[122880];
    const int tid = threadIdx.x;
    const float* mrow = masks + (size_t)t * NB;
    const float* mn   = masks + (size_t)(t + 1 < T ? t + 1 : t) * NB;
    const int b = blockIdx.x;

    if (b < 112) {          // ---- mono 64x256 tasks
        char* sA = smem;
        char* sB = smem + 24576;
        const int lane = tid & 63, w = tid >> 6;
        const int l15 = lane & 15, lg = lane >> 4;
        const int wr = w >> 2, wc = w & 3;
        if (b < 32) {       // Pfinal: out[t] += h@pWh
            const int row0 = (b >> 3) * 64, col0 = (b & 7) * 256;
            f32x4 acc[2][4] = {};
            mm256(tid, sA, sB, (const char*)hbm + (size_t)row0 * 2048,
                  Wb + (size_t)(R_PWH + col0) * 2048, acc);
            float* ob = out + (size_t)t * NB * TWOH;
            #pragma unroll
            for (int fc = 0; fc < 4; ++fc) {
                const int gc = col0 + wc * 64 + fc * 16 + l15;
                #pragma unroll
                for (int fr = 0; fr < 2; ++fr)
                    #pragma unroll
                    for (int j = 0; j < 4; ++j) {
                        const int n = row0 + wr * 32 + fr * 16 + lg * 4 + j;
                        const float v = ob[(size_t)n * TWOH + gc] + acc[fr][fc][j];
                        ob[(size_t)n * TWOH + gc] = v;
                        if (gc < 1024) st_bf_swz(pmub, n, gc, v);
                    }
            }
        } else if (b < 64) {    // Q
            const int i = b - 32;
            const int row0 = (i >> 3) * 64, col0 = (i & 7) * 256;
            f32x4 acc[2][4] = {};
            mm256(tid, sA, sB, (const char*)fbm + (size_t)row0 * 2048,
                  Wb + (size_t)(R_QWF + col0) * 2048, acc);
            float* ob = out + OFF_Q + (size_t)t * NB * TWOH;
            #pragma unroll
            for (int fc = 0; fc < 4; ++fc) {
                const int gc = col0 + wc * 64 + fc * 16 + l15;
                const float bb = qb[gc];
                #pragma unroll
                for (int fr = 0; fr < 2; ++fr)
                    #pragma unroll
                    for (int j = 0; j < 4; ++j) {
                        const int n = row0 + wr * 32 + fr * 16 + lg * 4 + j;
                        const float xq = ob[(size_t)n * TWOH + gc];
                        float v = acc[fr][fc][j] + mrow[n] * xq + bb;
                        ob[(size_t)n * TWOH + gc] = v;
                        if (gc < 1024) st_bf_swz(qmubN, n, gc, v * mn[n]);
                    }
            }
        } else {                // Shh
            const int i = b - 64;
            const int row0 = (i / 12) * 64, col0 = (i % 12) * 256;
            f32x4 acc[2][4] = {};
            mm256(tid, sA, sB, (const char*)hbm + (size_t)row0 * 2048,
                  Wb + (size_t)(R_HWHH + col0) * 2048, acc);
            #pragma unroll
            for (int fc = 0; fc < 4; ++fc) {
                const int gc = col0 + wc * 64 + fc * 16 + l15;
                #pragma unroll
                for (int fr = 0; fr < 2; ++fr)
                    #pragma unroll
                    for (int j = 0; j < 4; ++j) {
                        const int n = row0 + wr * 32 + fr * 16 + lg * 4 + j;
                        Shh[(size_t)n * THREEH + gc] = acc[fr][fc][j];
                    }
            }
        }
    } else {                // ---- paired f-GRU (2 tasks of 32x64)
        const int half = tid >> 8;
        const int ht = tid & 255;
        char* base = smem + half * 57344;
        const int task = (b - 112) * 2 + half;     // 0..127
        const int row0 = (task >> 4) * 32, col0 = (task & 15) * 64;
        const int lane = ht & 63, w = ht >> 6;
        const int l15 = lane & 15, lg = lane >> 4;
        const int wr = w >> 1, wc = w & 1;
        f32x4 aR[2] = {}, aZ[2] = {}, aN[2] = {};
        mm32g1(ht, base, base + 8192, (const char*)fbm + (size_t)row0 * 2048,
               Wb + (size_t)(R_FWHH + col0) * 2048, aR, aZ, aN);
        const __bf16* gsl = Gfb + (size_t)(t & 7) * NB * THREEH;
        #pragma unroll
        for (int fc = 0; fc < 2; ++fc) {
            const int col = col0 + wc * 32 + fc * 16 + l15;
            const float br  = fbih[col] + fbhh[col];
            const float bz  = fbih[col + 1024] + fbhh[col + 1024];
            const float bni = fbih[col + 2048], bnh = fbhh[col + 2048];
            #pragma unroll
            for (int j = 0; j < 4; ++j) {
                const int n = row0 + wr * 16 + lg * 4 + j;
                const float gfr = (float)gsl[(size_t)n * THREEH + col];
                const float gfz = (float)gsl[(size_t)n * THREEH + col + 1024];
                const float gfn = (float)gsl[(size_t)n * THREEH + col + 2048];
                const float rg = sigf(gfr + aR[fc][j] + br);
                const float zg = sigf(gfz + aZ[fc][j] + bz);
                const float ng = tanhf(gfn + bni + rg * (aN[fc][j] + bnh));
                const float fm = fstF[(size_t)n * 1024 + col] * mrow[n];
                const float o = (1.f - zg) * ng + zg * fm;
                fstN[(size_t)n * 1024 + col] = o;
                st_bf_swz(fbmN, n, col, o * mn[n]);
            }
        }
    }
}

// ---------------------------------------------------------------- per-step K2 (176 blocks x 512)
// [0,64) h-GRU pairs | [64,96) Pq(t+1) | [96,128) xq(t+LA) | [128,176) Gf(t+LA)
__global__ __launch_bounds__(512) void k2_k(
    int t,
    const __bf16* __restrict__ pmub, const __bf16* __restrict__ qmubN,
    const char* __restrict__ cbfB,
    const float* __restrict__ Shh,
    const float* __restrict__ hstF, float* __restrict__ hstN, __bf16* __restrict__ hbmN,
    const char* __restrict__ Wb,
    const float* __restrict__ hbih, const float* __restrict__ hbhh,
    const float* __restrict__ masks, const float* __restrict__ act,
    const float* __restrict__ pW, const float* __restrict__ pb,
    const float* __restrict__ qW,
    __bf16* __restrict__ Gfb, float* __restrict__ out)
{
    __shared__ char smem[122880];
    const int tid = threadIdx.x;
    const float* mrow = masks + (size_t)t * NB;
    const float* mn   = masks + (size_t)(t + 1 < T ? t + 1 : t) * NB;
    const int b = blockIdx.x;

    if (b < 64) {           // ---- paired h-GRU
        const int half = tid >> 8;
        const int ht = tid & 255;
        char* base = smem + half * 57344;
        const int task = b * 2 + half;             // 0..127
        const int row0 = (task >> 4) * 32, col0 = (task & 15) * 64;
        const int lane = ht & 63, w = ht >> 6;
        const int l15 = lane & 15, lg = lane >> 4;
        const int wr = w >> 1, wc = w & 1;
        f32x4 aR[2] = {}, aZ[2] = {}, aN[2] = {};
        mm32g1(ht, base, base + 8192, (const char*)pmub + (size_t)row0 * 2048,
               Wb + (size_t)(R_HWIH + col0) * 2048, aR, aZ, aN);
        #pragma unroll
        for (int fc = 0; fc < 2; ++fc) {
            const int col = col0 + wc * 32 + fc * 16 + l15;
            const float bri = hbih[col],        brh = hbhh[col];
            const float bzi = hbih[col + 1024], bzh = hbhh[col + 1024];
            const float bni = hbih[col + 2048], bnh = hbhh[col + 2048];
            #pragma unroll
            for (int j = 0; j < 4; ++j) {
                const int n = row0 + wr * 16 + lg * 4 + j;
                const float ghr = Shh[(size_t)n * THREEH + col];
                const float ghz = Shh[(size_t)n * THREEH + col + 1024];
                const float ghn = Shh[(size_t)n * THREEH + col + 2048];
                const float rg = sigf(aR[fc][j] + bri + ghr + brh);
                const float zg = sigf(aZ[fc][j] + bzi + ghz + bzh);
                const float ng = tanhf(aN[fc][j] + bni + rg * (ghn + bnh));
                const float hm = hstF[(size_t)n * 1024 + col] * mrow[n];
                const float o = (1.f - zg) * ng + zg * hm;
                hstN[(size_t)n * 1024 + col] = o;
                st_bf_swz(hbmN, n, col, o * mn[n]);
            }
        }
    } else if (b < 96) {    // ---- Pq partial for step t+1 (clamped; store gated)
        const bool wr_en = (t + 1 < T);
        const int tt = wr_en ? t + 1 : t;
        do_pq(tt, b - 64, tid, smem, smem + 24576, qmubN, Wb, masks, act, pW, pb, out, wr_en);
    } else if (b < 128) {   // ---- xq filler (clamped; store gated)
        const bool wr_en = (t + LA < T);
        const int s = wr_en ? t + LA : T - 1;
        do_xq(s, b - 96, tid, smem, smem + 24576, cbfB, Wb, act, qW, out, wr_en);
    } else {                // ---- Gf filler (clamped; store gated)
        const bool wr_en = (t + LA < T);
        const int s = wr_en ? t + LA : T - 1;
        do_gf(s, b - 128, tid, smem, smem + 24576, cbfB, Wb, Gfb, wr_en);
    }
}

// ---------------------------------------------------------------- final hxs
__global__ __launch_bounds__(256) void write_hxs_k(const float* __restrict__ fS,
                                                   const float* __restrict__ hS,
                                                   float* out) {
    const int i = blockIdx.x * 256 + threadIdx.x;
    const int n = i / THREEH;
    const int j = i - n * THREEH;
    float v;
    if (j < H)          v = fS[(size_t)n * H + j];
    else if (j < TWOH)  v = hS[(size_t)n * H + (j - H)];
    else                v = out[OFF_Q + ((size_t)(T - 1) * NB + n) * TWOH + (j - TWOH)];
    out[OFF_HX + i] = v;
}

// ---------------------------------------------------------------- launcher
extern "C" void kernel_launch(void* const* d_in, const int* in_sizes, int n_in,
                              void* d_out, int out_size, void* d_ws, size_t ws_size,
                              hipStream_t stream) {
    (void)in_sizes; (void)n_in; (void)out_size; (void)ws_size;

    const float* c     = (const float*)d_in[0];
    const float* hxs   = (const float*)d_in[1];
    const float* masks = (const float*)d_in[2];
    const float* act   = (const float*)d_in[3];
    const float* hWih  = (const float*)d_in[4];
    const float* hWhh  = (const float*)d_in[5];
    const float* hbih  = (const float*)d_in[6];
    const float* hbhh  = (const float*)d_in[7];
    const float* fWih  = (const float*)d_in[8];
    const float* fWhh  = (const float*)d_in[9];
    const float* fbih  = (const float*)d_in[10];
    const float* fbhh  = (const float*)d_in[11];
    const float* pW    = (const float*)d_in[12];
    const float* pb    = (const float*)d_in[13];
    const float* qW    = (const float*)d_in[14];
    const float* qb    = (const float*)d_in[15];

    float* out = (float*)d_out;
    char*  wsb = (char*)d_ws;

    __bf16* Wbf  = (__bf16*)(wsb);                               // 41.94 MB
    __bf16* cbf  = (__bf16*)(wsb + 41943040LL);                  // 33.55 MB
    float*  fst[2] = { (float*)(wsb + 75497472LL), (float*)(wsb + 76546048LL) };
    float*  hst[2] = { (float*)(wsb + 77594624LL), (float*)(wsb + 78643200LL) };
    __bf16* fbm[2] = { (__bf16*)(wsb + 79691776LL), (__bf16*)(wsb + 80216064LL) };
    __bf16* hbm[2] = { (__bf16*)(wsb + 80740352LL), (__bf16*)(wsb + 81264640LL) };
    __bf16* qmb[2] = { (__bf16*)(wsb + 81788928LL), (__bf16*)(wsb + 82313216LL) };
    __bf16* pmub   = (__bf16*)(wsb + 82837504LL);                // 0.52 MB
    float*  Shh    = (float*)(wsb + 83361792LL);                 // 3.15 MB
    __bf16* Gfb    = (__bf16*)(wsb + 86507520LL);                // 8 x 1.57 MB -> ~99.1 MB
    const char* Wb   = (const char*)Wbf;
    const char* cbfB = (const char*)cbf;

    wcvt_k <<<dim3(10240), dim3(256), 0, stream>>>(pW, qW, fWih, fWhh, hWih, hWhh, Wbf);
    ccvt_k <<<dim3(8192),  dim3(256), 0, stream>>>(c, cbf);
    init2_k<<<dim3(384),   dim3(256), 0, stream>>>(hxs, masks, fst[0], hst[0],
                                                   fbm[0], hbm[0], qmb[0]);
    pre_k  <<<dim3(LA * 80 + 32), dim3(512), 0, stream>>>(
        cbfB, Wb, act, qW, qmb[0], masks, pW, pb, Gfb, out);

    for (int t = 0; t < T; ++t) {
        const int cur = t & 1, nxt = cur ^ 1;
        k1_k<<<dim3(176), dim3(512), 0, stream>>>(
            t, hbm[cur], fbm[cur], qmb[nxt],
            masks, act, qb, qW, Wb, pmub, Shh, Gfb,
            fbih, fbhh, fst[cur], fst[nxt], fbm[nxt], out);
        k2_k<<<dim3(176), dim3(512), 0, stream>>>(
            t, pmub, qmb[nxt], cbfB, Shh,
            hst[cur], hst[nxt], hbm[nxt],
            Wb, hbih, hbhh, masks, act, pW, pb, qW, Gfb, out);
    }

    write_hxs_k<<<dim3(3072), dim3(256), 0, stream>>>(fst[0], hst[0], out);
}

// Round 14
// 2506.144 us; speedup vs baseline: 1.0094x; 1.0094x over previous
//
#include <hip/hip_runtime.h>
#include <math.h>

typedef __attribute__((ext_vector_type(8))) __bf16 bf16x8;
typedef __attribute__((ext_vector_type(4))) float f32x4;

constexpr int H = 1024, T = 64, NB = 256, TWOH = 2048, THREEH = 3072;
constexpr long long OFF_Q  = 33554432LL;
constexpr long long OFF_HX = 67108864LL;
constexpr int LA = 6;      // Gf lookahead (ring of 8 slices)

// Wbf row offsets (rows of 1024 bf16, byte stride 2048).
// pW/qW/fWih/hWhh standard; fWhh/hWih GATE-PACKED (16 tiles x 192 rows,
// each 48-row chunk = {r,z,n} x 16 cols).
constexpr int R_PWH = 0, R_PWQ = 2048, R_QWF = 4096, R_QWC = 6144,
              R_FWIH = 8192, R_FWHH = 11264, R_HWIH = 14336, R_HWHH = 17408;

#define LD4(p) (*reinterpret_cast<const float4*>(p))

__device__ __forceinline__ float sigf(float x) { return 1.0f / (1.0f + expf(-x)); }

__device__ __forceinline__ void gload16(const void* g, void* l) {
    __builtin_amdgcn_global_load_lds(
        (const __attribute__((address_space(1))) uint32_t*)g,
        (__attribute__((address_space(3))) uint32_t*)l, 16, 0, 0);
}

__device__ __forceinline__ void st_bf_swz(__bf16* base, int n, int k, float v) {
    base[(size_t)n * 1024 + (((k >> 3) ^ (n & 7)) << 3) + (k & 7)] = (__bf16)v;
}

#define FRAGOFF(rloc, gl) (((rloc) << 7) + ((((gl)) ^ ((rloc) & 7)) << 4))

// stage RT rows x 64 k from pre-swizzled global (row stride 2048B) into LDS
template<int RT>
__device__ __forceinline__ void stage_tile(const char* g, char* l, int kb, int tid) {
    #pragma unroll
    for (int i = 0; i < RT / 32; ++i) {
        const int L = i * 4096 + tid * 16;
        gload16(g + (size_t)(L >> 7) * 2048 + (size_t)kb * 128 + (L & 127), l + L);
    }
}

// ---------------------------------------------------------------- 64x128 GEMM core
// r8-proven: 3-deep, vmcnt(12)/(6)/(0). sA: 3 x 8KB, sB: 3 x 16KB (72KB).
__device__ __forceinline__ void mm128(
    int tid, char* sA, char* sB,
    const char* A, const char* B,
    f32x4 (&acc)[2][4])
{
    const int lane = tid & 63, w = tid >> 6;
    const int l15 = lane & 15, lg = lane >> 4;
    const int wr = w >> 1, wc = w & 1;
    int aoff[2][2], boff[4][2];
    #pragma unroll
    for (int fr = 0; fr < 2; ++fr)
        #pragma unroll
        for (int kk = 0; kk < 2; ++kk)
            aoff[fr][kk] = FRAGOFF(wr * 32 + fr * 16 + l15, kk * 4 + lg);
    #pragma unroll
    for (int fc = 0; fc < 4; ++fc)
        #pragma unroll
        for (int kk = 0; kk < 2; ++kk)
            boff[fc][kk] = FRAGOFF(wc * 64 + fc * 16 + l15, kk * 4 + lg);

    stage_tile<64>(A, sA, 0, tid);
    stage_tile<128>(B, sB, 0, tid);
    stage_tile<64>(A, sA + 8192, 1, tid);
    stage_tile<128>(B, sB + 16384, 1, tid);
    for (int kb = 0; kb < 16; ++kb) {
        const int kn = kb + 2;
        if (kn < 16) {
            const int bo = kn % 3;
            stage_tile<64>(A, sA + bo * 8192, kn, tid);
            stage_tile<128>(B, sB + bo * 16384, kn, tid);
            asm volatile("s_waitcnt vmcnt(12)" ::: "memory");
        } else if (kb + 1 < 16) {
            asm volatile("s_waitcnt vmcnt(6)" ::: "memory");
        } else {
            asm volatile("s_waitcnt vmcnt(0)" ::: "memory");
        }
        __builtin_amdgcn_s_barrier();
        __builtin_amdgcn_sched_barrier(0);
        const int bc = kb % 3;
        char* Ab = sA + bc * 8192;
        char* Bb = sB + bc * 16384;
        bf16x8 af[2][2], bv[4][2];
        #pragma unroll
        for (int fr = 0; fr < 2; ++fr)
            #pragma unroll
            for (int kk = 0; kk < 2; ++kk)
                af[fr][kk] = *reinterpret_cast<const bf16x8*>(Ab + aoff[fr][kk]);
        #pragma unroll
        for (int fc = 0; fc < 4; ++fc)
            #pragma unroll
            for (int kk = 0; kk < 2; ++kk)
                bv[fc][kk] = *reinterpret_cast<const bf16x8*>(Bb + boff[fc][kk]);
        __builtin_amdgcn_s_setprio(1);
        #pragma unroll
        for (int kk = 0; kk < 2; ++kk)
            #pragma unroll
            for (int fr = 0; fr < 2; ++fr)
                #pragma unroll
                for (int fc = 0; fc < 4; ++fc)
                    acc[fr][fc] = __builtin_amdgcn_mfma_f32_16x16x32_bf16(
                        af[fr][kk], bv[fc][kk], acc[fr][fc], 0, 0, 0);
        __builtin_amdgcn_s_setprio(0);
        __builtin_amdgcn_s_barrier();
        __builtin_amdgcn_sched_barrier(0);
    }
}

// ---------------------------------------------------------------- 64-row 3-gate core
// Gate-packed B (192 rows/tile: chunk c = cols [c*16,c*16+16) x gates {r,z,n}).
// Same 2-deep schedule as proven mm32g1; 8 loads/stage -> vmcnt(8)/(0).
// sA: 2 x 8KB, sB: 2 x 24KB (64KB). Thread holds r,z,n for SAME col (gate=fc%3).
__device__ __forceinline__ void mm64g(
    int tid, char* sA, char* sB,
    const char* A, const char* Bp,
    f32x4 (&aR)[2][2], f32x4 (&aZ)[2][2], f32x4 (&aN)[2][2])
{
    const int lane = tid & 63, w = tid >> 6;
    const int l15 = lane & 15, lg = lane >> 4;
    const int wr = w >> 1, wc = w & 1;
    int aoff[2][2], boff[2][3][2];
    #pragma unroll
    for (int fr = 0; fr < 2; ++fr)
        #pragma unroll
        for (int kk = 0; kk < 2; ++kk)
            aoff[fr][kk] = FRAGOFF(wr * 32 + fr * 16 + l15, kk * 4 + lg);
    #pragma unroll
    for (int cb = 0; cb < 2; ++cb)
        #pragma unroll
        for (int g = 0; g < 3; ++g)
            #pragma unroll
            for (int kk = 0; kk < 2; ++kk) {
                const int v = wc * 96 + (cb * 3 + g) * 16 + l15;   // packed row
                boff[cb][g][kk] = FRAGOFF(v, kk * 4 + lg);
            }
    auto stg = [&](int buf, int kb) {
        stage_tile<64>(A, sA + buf * 8192, kb, tid);
        stage_tile<192>(Bp, sB + buf * 24576, kb, tid);
    };
    stg(0, 0);
    for (int kb = 0; kb < 16; ++kb) {
        if (kb + 1 < 16) {
            stg((kb + 1) & 1, kb + 1);
            asm volatile("s_waitcnt vmcnt(8)" ::: "memory");
        } else {
            asm volatile("s_waitcnt vmcnt(0)" ::: "memory");
        }
        __builtin_amdgcn_s_barrier();
        __builtin_amdgcn_sched_barrier(0);
        char* Ab = sA + (kb & 1) * 8192;
        char* Bb = sB + (kb & 1) * 24576;
        bf16x8 af[2][2];
        #pragma unroll
        for (int fr = 0; fr < 2; ++fr)
            #pragma unroll
            for (int kk = 0; kk < 2; ++kk)
                af[fr][kk] = *reinterpret_cast<const bf16x8*>(Ab + aoff[fr][kk]);
        bf16x8 bv[2][3][2];
        #pragma unroll
        for (int cb = 0; cb < 2; ++cb)
            #pragma unroll
            for (int g = 0; g < 3; ++g)
                #pragma unroll
                for (int kk = 0; kk < 2; ++kk)
                    bv[cb][g][kk] = *reinterpret_cast<const bf16x8*>(Bb + boff[cb][g][kk]);
        __builtin_amdgcn_s_setprio(1);
        #pragma unroll
        for (int kk = 0; kk < 2; ++kk)
            #pragma unroll
            for (int fr = 0; fr < 2; ++fr)
                #pragma unroll
                for (int cb = 0; cb < 2; ++cb) {
                    aR[fr][cb] = __builtin_amdgcn_mfma_f32_16x16x32_bf16(
                        af[fr][kk], bv[cb][0][kk], aR[fr][cb], 0, 0, 0);
                    aZ[fr][cb] = __builtin_amdgcn_mfma_f32_16x16x32_bf16(
                        af[fr][kk], bv[cb][1][kk], aZ[fr][cb], 0, 0, 0);
                    aN[fr][cb] = __builtin_amdgcn_mfma_f32_16x16x32_bf16(
                        af[fr][kk], bv[cb][2][kk], aN[fr][cb], 0, 0, 0);
                }
        __builtin_amdgcn_s_setprio(0);
        __builtin_amdgcn_s_barrier();
        __builtin_amdgcn_sched_barrier(0);
    }
}

// ---------------------------------------------------------------- shared bodies
// xq: out_q[slice] = c@qWc^T + a@qWa^T (raw). 64 tasks/slice.
__device__ __forceinline__ void do_xq(int slice, int i, int tid, char* sA, char* sB,
    const char* cbfB, const char* Wb, const float* act, const float* qW, float* out)
{
    const int lane = tid & 63, w = tid >> 6;
    const int l15 = lane & 15, lg = lane >> 4;
    const int wr = w >> 1, wc = w & 1;
    const int row0 = (i >> 4) * 64, col0 = (i & 15) * 128;
    const size_t grow0 = (size_t)slice * NB + row0;
    f32x4 acc[2][4] = {};
    mm128(tid, sA, sB, cbfB + grow0 * 2048, Wb + (size_t)(R_QWC + col0) * 2048, acc);
    #pragma unroll
    for (int fc = 0; fc < 4; ++fc) {
        const int gc = col0 + wc * 64 + fc * 16 + l15;
        const float* wp = qW + (size_t)gc * 2056 + 2048;
        float4 x0 = LD4(wp), x1 = LD4(wp + 4);
        #pragma unroll
        for (int fr = 0; fr < 2; ++fr)
            #pragma unroll
            for (int j = 0; j < 4; ++j) {
                const size_t n = grow0 + wr * 32 + fr * 16 + lg * 4 + j;
                const float* ar = act + n * 8;
                float4 a0 = LD4(ar), a1 = LD4(ar + 4);
                float dot = a0.x * x0.x + a0.y * x0.y + a0.z * x0.z + a0.w * x0.w
                          + a1.x * x1.x + a1.y * x1.y + a1.z * x1.z + a1.w * x1.w;
                out[OFF_Q + n * TWOH + gc] = acc[fr][fc][j] + dot;
            }
    }
}

// Gf: Gfb[slot] = c_t@fWih^T (bf16 ring). 96 tasks/slice.
__device__ __forceinline__ void do_gf(int slice, int i, int tid, char* sA, char* sB,
    const char* cbfB, const char* Wb, __bf16* Gfb)
{
    const int lane = tid & 63, w = tid >> 6;
    const int l15 = lane & 15, lg = lane >> 4;
    const int wr = w >> 1, wc = w & 1;
    const int row0 = (i / 24) * 64, col0 = (i % 24) * 128;
    f32x4 acc[2][4] = {};
    mm128(tid, sA, sB, cbfB + ((size_t)slice * NB + row0) * 2048,
          Wb + (size_t)(R_FWIH + col0) * 2048, acc);
    __bf16* gdst = Gfb + (size_t)(slice & 7) * NB * THREEH;
    #pragma unroll
    for (int fc = 0; fc < 4; ++fc) {
        const int gc = col0 + wc * 64 + fc * 16 + l15;
        #pragma unroll
        for (int fr = 0; fr < 2; ++fr)
            #pragma unroll
            for (int j = 0; j < 4; ++j) {
                const int n = row0 + wr * 32 + fr * 16 + lg * 4 + j;
                gdst[(size_t)n * THREEH + gc] = (__bf16)acc[fr][fc][j];
            }
    }
}

// Pq partial: out_p[tt] = qmu(tt)@pWq^T + m*a@pWa^T + pb. 64 tasks.
__device__ __forceinline__ void do_pq(int tt, int i, int tid, char* sA, char* sB,
    const __bf16* qmu_t, const char* Wb, const float* masks, const float* act,
    const float* pW, const float* pb, float* out)
{
    const int lane = tid & 63, w = tid >> 6;
    const int l15 = lane & 15, lg = lane >> 4;
    const int wr = w >> 1, wc = w & 1;
    const int row0 = (i >> 4) * 64, col0 = (i & 15) * 128;
    f32x4 acc[2][4] = {};
    mm128(tid, sA, sB, (const char*)qmu_t + (size_t)row0 * 2048,
          Wb + (size_t)(R_PWQ + col0) * 2048, acc);
    const float* mrow = masks + (size_t)tt * NB;
    float* ob = out + (size_t)tt * NB * TWOH;
    #pragma unroll
    for (int fc = 0; fc < 4; ++fc) {
        const int gc = col0 + wc * 64 + fc * 16 + l15;
        const float* wp = pW + (size_t)gc * 2056 + 2048;
        float4 x0 = LD4(wp), x1 = LD4(wp + 4);
        const float bb = pb[gc];
        #pragma unroll
        for (int fr = 0; fr < 2; ++fr)
            #pragma unroll
            for (int j = 0; j < 4; ++j) {
                const int n = row0 + wr * 32 + fr * 16 + lg * 4 + j;
                const float* ar = act + ((size_t)tt * NB + n) * 8;
                float4 a0 = LD4(ar), a1 = LD4(ar + 4);
                float dot = a0.x * x0.x + a0.y * x0.y + a0.z * x0.z + a0.w * x0.w
                          + a1.x * x1.x + a1.y * x1.y + a1.z * x1.z + a1.w * x1.w;
                ob[(size_t)n * TWOH + gc] = acc[fr][fc][j] + mrow[n] * dot + bb;
            }
    }
}

// ---------------------------------------------------------------- prepass kernels
__global__ __launch_bounds__(256) void wcvt_k(
    const float* __restrict__ pW, const float* __restrict__ qW,
    const float* __restrict__ fWih, const float* __restrict__ fWhh,
    const float* __restrict__ hWih, const float* __restrict__ hWhh,
    __bf16* __restrict__ Wbf)
{
    const long i = (long)blockIdx.x * 256 + threadIdx.x;
    const int row = (int)(i >> 7);
    const int G   = (int)i & 127;
    const float* src; int stride; int koff = 0; int r;
    if (row < 2048)       { src = pW;   stride = 2056; koff = 0;    r = row; }
    else if (row < 4096)  { src = pW;   stride = 2056; koff = 1024; r = row - 2048; }
    else if (row < 6144)  { src = qW;   stride = 2056; koff = 0;    r = row - 4096; }
    else if (row < 8192)  { src = qW;   stride = 2056; koff = 1024; r = row - 6144; }
    else if (row < 11264) { src = fWih; stride = 1024; r = row - 8192; }
    else if (row < 14336) {             // fWhh GATE-PACKED
        const int rp = row - 11264;
        const int j = rp / 192, rem = rp % 192;
        const int chunk = rem / 48, rem2 = rem % 48;
        const int g = rem2 >> 4, cc = rem2 & 15;
        src = fWhh; stride = 1024; r = g * 1024 + j * 64 + chunk * 16 + cc;
    }
    else if (row < 17408) {             // hWih GATE-PACKED
        const int rp = row - 14336;
        const int j = rp / 192, rem = rp % 192;
        const int chunk = rem / 48, rem2 = rem % 48;
        const int g = rem2 >> 4, cc = rem2 & 15;
        src = hWih; stride = 1024; r = g * 1024 + j * 64 + chunk * 16 + cc;
    }
    else                  { src = hWhh; stride = 1024; r = row - 17408; }
    const float* p = src + (long)r * stride + koff + G * 8;
    float4 a = LD4(p), b = LD4(p + 4);
    bf16x8 v;
    v[0] = (__bf16)a.x; v[1] = (__bf16)a.y; v[2] = (__bf16)a.z; v[3] = (__bf16)a.w;
    v[4] = (__bf16)b.x; v[5] = (__bf16)b.y; v[6] = (__bf16)b.z; v[7] = (__bf16)b.w;
    *reinterpret_cast<bf16x8*>(Wbf + (size_t)row * 1024 + ((G ^ (row & 7)) << 3)) = v;
}

__global__ __launch_bounds__(256) void ccvt_k(const float* __restrict__ c,
                                              __bf16* __restrict__ cbf) {
    const long i = (long)blockIdx.x * 256 + threadIdx.x;
    const int row = (int)(i >> 7);
    const int G   = (int)i & 127;
    const float* p = c + (size_t)row * 1024 + G * 8;
    float4 a = LD4(p), b = LD4(p + 4);
    bf16x8 v;
    v[0] = (__bf16)a.x; v[1] = (__bf16)a.y; v[2] = (__bf16)a.z; v[3] = (__bf16)a.w;
    v[4] = (__bf16)b.x; v[5] = (__bf16)b.y; v[6] = (__bf16)b.z; v[7] = (__bf16)b.w;
    *reinterpret_cast<bf16x8*>(cbf + (size_t)row * 1024 + ((G ^ (row & 7)) << 3)) = v;
}

__global__ __launch_bounds__(256) void init2_k(
    const float* __restrict__ hxs, const float* __restrict__ masks,
    float* __restrict__ fst0, float* __restrict__ hst0,
    __bf16* __restrict__ fbm0, __bf16* __restrict__ hbm0, __bf16* __restrict__ qmub0)
{
    const int idx = blockIdx.x * 256 + threadIdx.x;
    const int arr = idx >> 15;
    const int g   = idx & 32767;
    const int n   = g >> 7;
    const int G   = g & 127;
    const float m0 = masks[n];
    const float* p = hxs + (size_t)n * THREEH + arr * 1024 + G * 8;
    float4 a = LD4(p), b = LD4(p + 4);
    __bf16* dstB = arr == 0 ? fbm0 : (arr == 1 ? hbm0 : qmub0);
    bf16x8 v;
    v[0] = (__bf16)(a.x * m0); v[1] = (__bf16)(a.y * m0);
    v[2] = (__bf16)(a.z * m0); v[3] = (__bf16)(a.w * m0);
    v[4] = (__bf16)(b.x * m0); v[5] = (__bf16)(b.y * m0);
    v[6] = (__bf16)(b.z * m0); v[7] = (__bf16)(b.w * m0);
    *reinterpret_cast<bf16x8*>(dstB + (size_t)n * 1024 + ((G ^ (n & 7)) << 3)) = v;
    if (arr < 2) {
        float* dstF = arr == 0 ? fst0 : hst0;
        *reinterpret_cast<float4*>(dstF + (size_t)n * 1024 + G * 8) = a;
        *reinterpret_cast<float4*>(dstF + (size_t)n * 1024 + G * 8 + 4) = b;
    }
}

// ALL xq slices (4096) + Gf slices 0..LA-1 (LA*96) + Pq(0) (64)
__global__ __launch_bounds__(256) void pre_k(
    const char* __restrict__ cbfB, const char* __restrict__ Wb,
    const float* __restrict__ act, const float* __restrict__ qW,
    const __bf16* __restrict__ qmb0, const float* __restrict__ masks,
    const float* __restrict__ pW, const float* __restrict__ pb,
    __bf16* __restrict__ Gfb, float* __restrict__ out)
{
    __shared__ char smem[73728];
    const int b = blockIdx.x;
    if (b < 4096) {
        do_xq(b >> 6, b & 63, threadIdx.x, smem, smem + 24576, cbfB, Wb, act, qW, out);
    } else if (b < 4096 + LA * 96) {
        const int r = b - 4096;
        do_gf(r / 96, r % 96, threadIdx.x, smem, smem + 24576, cbfB, Wb, Gfb);
    } else {
        do_pq(0, b - 4096 - LA * 96, threadIdx.x, smem, smem + 24576,
              qmb0, Wb, masks, act, pW, pb, out);
    }
}

// ---------------------------------------------------------------- per-step K1 (256)
// [0,64) Pfinal | [64,128) Q | [128,224) Shh | [224,256) Gf(t+LA) tasks 0..31
__global__ __launch_bounds__(256) void k1_k(
    int t,
    const __bf16* __restrict__ hbm, const __bf16* __restrict__ fbm,
    __bf16* __restrict__ qmubN, const char* __restrict__ cbfB,
    const float* __restrict__ masks, const float* __restrict__ act,
    const float* __restrict__ qb, const float* __restrict__ qW,
    const char* __restrict__ Wb,
    __bf16* __restrict__ pmub, float* __restrict__ Shh,
    __bf16* __restrict__ Gfb,
    float* __restrict__ out)
{
    __shared__ char smem[73728];
    char* sA = smem;
    char* sB = smem + 24576;
    const int tid = threadIdx.x;
    const int lane = tid & 63, w = tid >> 6;
    const int l15 = lane & 15, lg = lane >> 4;
    const int wr = w >> 1, wc = w & 1;
    const float* mrow = masks + (size_t)t * NB;
    const float* mn   = masks + (size_t)(t + 1 < T ? t + 1 : t) * NB;
    int b = blockIdx.x;

    if (b < 64) {           // ---- Pfinal: out[t] += h@pWh
        const int row0 = (b >> 4) * 64, col0 = (b & 15) * 128;
        f32x4 acc[2][4] = {};
        mm128(tid, sA, sB, (const char*)hbm + (size_t)row0 * 2048,
              Wb + (size_t)(R_PWH + col0) * 2048, acc);
        float* ob = out + (size_t)t * NB * TWOH;
        #pragma unroll
        for (int fc = 0; fc < 4; ++fc) {
            const int gc = col0 + wc * 64 + fc * 16 + l15;
            #pragma unroll
            for (int fr = 0; fr < 2; ++fr)
                #pragma unroll
                for (int j = 0; j < 4; ++j) {
                    const int n = row0 + wr * 32 + fr * 16 + lg * 4 + j;
                    const float v = ob[(size_t)n * TWOH + gc] + acc[fr][fc][j];
                    ob[(size_t)n * TWOH + gc] = v;
                    if (gc < 1024) st_bf_swz(pmub, n, gc, v);
                }
        }
    } else if (b < 128) {   // ---- Q
        b -= 64;
        const int row0 = (b >> 4) * 64, col0 = (b & 15) * 128;
        f32x4 acc[2][4] = {};
        mm128(tid, sA, sB, (const char*)fbm + (size_t)row0 * 2048,
              Wb + (size_t)(R_QWF + col0) * 2048, acc);
        float* ob = out + OFF_Q + (size_t)t * NB * TWOH;
        #pragma unroll
        for (int fc = 0; fc < 4; ++fc) {
            const int gc = col0 + wc * 64 + fc * 16 + l15;
            const float bb = qb[gc];
            #pragma unroll
            for (int fr = 0; fr < 2; ++fr)
                #pragma unroll
                for (int j = 0; j < 4; ++j) {
                    const int n = row0 + wr * 32 + fr * 16 + lg * 4 + j;
                    const float xq = ob[(size_t)n * TWOH + gc];
                    float v = acc[fr][fc][j] + mrow[n] * xq + bb;
                    ob[(size_t)n * TWOH + gc] = v;
                    if (gc < 1024) st_bf_swz(qmubN, n, gc, v * mn[n]);
                }
        }
    } else if (b < 224) {   // ---- h@hWhh -> Shh
        const int i = b - 128;
        const int row0 = (i / 24) * 64, col0 = (i % 24) * 128;
        f32x4 acc[2][4] = {};
        mm128(tid, sA, sB, (const char*)hbm + (size_t)row0 * 2048,
              Wb + (size_t)(R_HWHH + col0) * 2048, acc);
        #pragma unroll
        for (int fc = 0; fc < 4; ++fc) {
            const int gc = col0 + wc * 64 + fc * 16 + l15;
            #pragma unroll
            for (int fr = 0; fr < 2; ++fr)
                #pragma unroll
                for (int j = 0; j < 4; ++j) {
                    const int n = row0 + wr * 32 + fr * 16 + lg * 4 + j;
                    Shh[(size_t)n * THREEH + gc] = acc[fr][fc][j];
                }
        }
    } else {                // ---- Gf(t+LA) tasks 0..31
        if (t + LA < T)
            do_gf(t + LA, b - 224, tid, sA, sB, cbfB, Wb, Gfb);
    }
}

// ---------------------------------------------------------------- per-step K2 (256)
// [0,64) h-GRU | [64,128) f-GRU | [128,192) Pq(t+1) | [192,256) Gf(t+LA) tasks 32..95
__global__ __launch_bounds__(256) void k2_k(
    int t,
    const __bf16* __restrict__ pmub, const __bf16* __restrict__ qmubN,
    const __bf16* __restrict__ fbm, const char* __restrict__ cbfB,
    const float* __restrict__ Shh,
    const float* __restrict__ hstF, float* __restrict__ hstN, __bf16* __restrict__ hbmN,
    const float* __restrict__ fstF, float* __restrict__ fstN, __bf16* __restrict__ fbmN,
    const char* __restrict__ Wb,
    const float* __restrict__ hbih, const float* __restrict__ hbhh,
    const float* __restrict__ fbih, const float* __restrict__ fbhh,
    const float* __restrict__ masks, const float* __restrict__ act,
    const float* __restrict__ pW, const float* __restrict__ pb,
    const float* __restrict__ qW,
    __bf16* __restrict__ Gfb, float* __restrict__ out)
{
    __shared__ char smem[73728];
    char* sA = smem;
    char* sB = smem + 24576;
    const int tid = threadIdx.x;
    const int lane = tid & 63, w = tid >> 6;
    const int l15 = lane & 15, lg = lane >> 4;
    const int wr = w >> 1, wc = w & 1;
    const float* mrow = masks + (size_t)t * NB;
    const float* mn   = masks + (size_t)(t + 1 < T ? t + 1 : t) * NB;
    const int b = blockIdx.x;

    if (b < 64) {           // ---- h-GRU: pmu@hWih(packed) + Shh + combine
        const int row0 = (b >> 4) * 64, col0 = (b & 15) * 64;
        f32x4 aR[2][2] = {}, aZ[2][2] = {}, aN[2][2] = {};
        mm64g(tid, sA, sB, (const char*)pmub + (size_t)row0 * 2048,
              Wb + (size_t)(R_HWIH + (b & 15) * 192) * 2048, aR, aZ, aN);
        #pragma unroll
        for (int cb = 0; cb < 2; ++cb) {
            const int col = col0 + wc * 32 + cb * 16 + l15;
            const float bri = hbih[col],        brh = hbhh[col];
            const float bzi = hbih[col + 1024], bzh = hbhh[col + 1024];
            const float bni = hbih[col + 2048], bnh = hbhh[col + 2048];
            #pragma unroll
            for (int fr = 0; fr < 2; ++fr)
                #pragma unroll
                for (int j = 0; j < 4; ++j) {
                    const int n = row0 + wr * 32 + fr * 16 + lg * 4 + j;
                    const float ghr = Shh[(size_t)n * THREEH + col];
                    const float ghz = Shh[(size_t)n * THREEH + col + 1024];
                    const float ghn = Shh[(size_t)n * THREEH + col + 2048];
                    const float rg = sigf(aR[fr][cb][j] + bri + ghr + brh);
                    const float zg = sigf(aZ[fr][cb][j] + bzi + ghz + bzh);
                    const float ng = tanhf(aN[fr][cb][j] + bni + rg * (ghn + bnh));
                    const float hm = hstF[(size_t)n * 1024 + col] * mrow[n];
                    const float o = (1.f - zg) * ng + zg * hm;
                    hstN[(size_t)n * 1024 + col] = o;
                    st_bf_swz(hbmN, n, col, o * mn[n]);
                }
        }
    } else if (b < 128) {   // ---- f-GRU: f@fWhh(packed) + Gf ring + combine
        const int i = b - 64;
        const int row0 = (i >> 4) * 64, col0 = (i & 15) * 64;
        f32x4 aR[2][2] = {}, aZ[2][2] = {}, aN[2][2] = {};
        mm64g(tid, sA, sB, (const char*)fbm + (size_t)row0 * 2048,
              Wb + (size_t)(R_FWHH + (i & 15) * 192) * 2048, aR, aZ, aN);
        const __bf16* gsl = Gfb + (size_t)(t & 7) * NB * THREEH;
        #pragma unroll
        for (int cb = 0; cb < 2; ++cb) {
            const int col = col0 + wc * 32 + cb * 16 + l15;
            const float br  = fbih[col] + fbhh[col];
            const float bz  = fbih[col + 1024] + fbhh[col + 1024];
            const float bni = fbih[col + 2048], bnh = fbhh[col + 2048];
            #pragma unroll
            for (int fr = 0; fr < 2; ++fr)
                #pragma unroll
                for (int j = 0; j < 4; ++j) {
                    const int n = row0 + wr * 32 + fr * 16 + lg * 4 + j;
                    const float gfr = (float)gsl[(size_t)n * THREEH + col];
                    const float gfz = (float)gsl[(size_t)n * THREEH + col + 1024];
                    const float gfn = (float)gsl[(size_t)n * THREEH + col + 2048];
                    const float rg = sigf(gfr + aR[fr][cb][j] + br);
                    const float zg = sigf(gfz + aZ[fr][cb][j] + bz);
                    const float ng = tanhf(gfn + bni + rg * (aN[fr][cb][j] + bnh));
                    const float fm = fstF[(size_t)n * 1024 + col] * mrow[n];
                    const float o = (1.f - zg) * ng + zg * fm;
                    fstN[(size_t)n * 1024 + col] = o;
                    st_bf_swz(fbmN, n, col, o * mn[n]);
                }
        }
    } else if (b < 192) {   // ---- Pq partial for step t+1
        if (t + 1 < T)
            do_pq(t + 1, b - 128, tid, sA, sB, qmubN, Wb, masks, act, pW, pb, out);
    } else {                // ---- Gf(t+LA) tasks 32..95
        if (t + LA < T)
            do_gf(t + LA, (b - 192) + 32, tid, sA, sB, cbfB, Wb, Gfb);
    }
}

// ---------------------------------------------------------------- final hxs
__global__ __launch_bounds__(256) void write_hxs_k(const float* __restrict__ fS,
                                                   const float* __restrict__ hS,
                                                   float* out) {
    const int i = blockIdx.x * 256 + threadIdx.x;
    const int n = i / THREEH;
    const int j = i - n * THREEH;
    float v;
    if (j < H)          v = fS[(size_t)n * H + j];
    else if (j < TWOH)  v = hS[(size_t)n * H + (j - H)];
    else                v = out[OFF_Q + ((size_t)(T - 1) * NB + n) * TWOH + (j - TWOH)];
    out[OFF_HX + i] = v;
}

// ---------------------------------------------------------------- launcher
extern "C" void kernel_launch(void* const* d_in, const int* in_sizes, int n_in,
                              void* d_out, int out_size, void* d_ws, size_t ws_size,
                              hipStream_t stream) {
    (void)in_sizes; (void)n_in; (void)out_size; (void)ws_size;

    const float* c     = (const float*)d_in[0];
    const float* hxs   = (const float*)d_in[1];
    const float* masks = (const float*)d_in[2];
    const float* act   = (const float*)d_in[3];
    const float* hWih  = (const float*)d_in[4];
    const float* hWhh  = (const float*)d_in[5];
    const float* hbih  = (const float*)d_in[6];
    const float* hbhh  = (const float*)d_in[7];
    const float* fWih  = (const float*)d_in[8];
    const float* fWhh  = (const float*)d_in[9];
    const float* fbih  = (const float*)d_in[10];
    const float* fbhh  = (const float*)d_in[11];
    const float* pW    = (const float*)d_in[12];
    const float* pb    = (const float*)d_in[13];
    const float* qW    = (const float*)d_in[14];
    const float* qb    = (const float*)d_in[15];

    float* out = (float*)d_out;
    char*  wsb = (char*)d_ws;

    __bf16* Wbf  = (__bf16*)(wsb);                               // 41.94 MB
    __bf16* cbf  = (__bf16*)(wsb + 41943040LL);                  // 33.55 MB
    float*  fst[2] = { (float*)(wsb + 75497472LL), (float*)(wsb + 76546048LL) };
    float*  hst[2] = { (float*)(wsb + 77594624LL), (float*)(wsb + 78643200LL) };
    __bf16* fbm[2] = { (__bf16*)(wsb + 79691776LL), (__bf16*)(wsb + 80216064LL) };
    __bf16* hbm[2] = { (__bf16*)(wsb + 80740352LL), (__bf16*)(wsb + 81264640LL) };
    __bf16* qmb[2] = { (__bf16*)(wsb + 81788928LL), (__bf16*)(wsb + 82313216LL) };
    __bf16* pmub   = (__bf16*)(wsb + 82837504LL);                // 0.52 MB
    float*  Shh    = (float*)(wsb + 83361792LL);                 // 3.15 MB
    __bf16* Gfb    = (__bf16*)(wsb + 86507520LL);                // 8 x 1.57 MB -> ~99.1 MB
    const char* Wb   = (const char*)Wbf;
    const char* cbfB = (const char*)cbf;

    wcvt_k <<<dim3(10240), dim3(256), 0, stream>>>(pW, qW, fWih, fWhh, hWih, hWhh, Wbf);
    ccvt_k <<<dim3(8192),  dim3(256), 0, stream>>>(c, cbf);
    init2_k<<<dim3(384),   dim3(256), 0, stream>>>(hxs, masks, fst[0], hst[0],
                                                   fbm[0], hbm[0], qmb[0]);
    pre_k  <<<dim3(4096 + LA * 96 + 64), dim3(256), 0, stream>>>(
        cbfB, Wb, act, qW, qmb[0], masks, pW, pb, Gfb, out);

    for (int t = 0; t < T; ++t) {
        const int cur = t & 1, nxt = cur ^ 1;
        k1_k<<<dim3(256), dim3(256), 0, stream>>>(
            t, hbm[cur], fbm[cur], qmb[nxt], cbfB,
            masks, act, qb, qW, Wb, pmub, Shh, Gfb, out);
        k2_k<<<dim3(256), dim3(256), 0, stream>>>(
            t, pmub, qmb[nxt], fbm[cur], cbfB, Shh,
            hst[cur], hst[nxt], hbm[nxt],
            fst[cur], fst[nxt], fbm[nxt],
            Wb, hbih, hbhh, fbih, fbhh, masks, act, pW, pb, qW, Gfb, out);
    }

    write_hxs_k<<<dim3(3072), dim3(256), 0, stream>>>(fst[0], hst[0], out);
}

// Round 15
// 2104.330 us; speedup vs baseline: 1.2021x; 1.1909x over previous
//
#include <hip/hip_runtime.h>
#include <math.h>

typedef __attribute__((ext_vector_type(8))) __bf16 bf16x8;
typedef __attribute__((ext_vector_type(4))) float f32x4;

constexpr int H = 1024, T = 64, NB = 256, TWOH = 2048, THREEH = 3072;
constexpr long long OFF_Q  = 33554432LL;
constexpr long long OFF_HX = 67108864LL;
constexpr int LA = 6;      // filler lookahead (ring of 8 slices)

// Wbf row offsets (rows of 1024 bf16, byte stride 2048). Swizzled (staged via LDS).
constexpr int R_PWH = 0, R_PWQ = 2048, R_QWF = 4096, R_QWC = 6144,
              R_FWIH = 8192, R_FWHH = 11264, R_HWIH = 14336, R_HWHH = 17408;

#define LD4(p) (*reinterpret_cast<const float4*>(p))

__device__ __forceinline__ float sigf(float x) { return 1.0f / (1.0f + expf(-x)); }

__device__ __forceinline__ void gload16(const void* g, void* l) {
    __builtin_amdgcn_global_load_lds(
        (const __attribute__((address_space(1))) uint32_t*)g,
        (__attribute__((address_space(3))) uint32_t*)l, 16, 0, 0);
}

__device__ __forceinline__ void st_bf_swz(__bf16* base, int n, int k, float v) {
    base[(size_t)n * 1024 + (((k >> 3) ^ (n & 7)) << 3) + (k & 7)] = (__bf16)v;
}

#define FRAGOFF(rloc, gl) (((rloc) << 7) + ((((gl)) ^ ((rloc) & 7)) << 4))

// stage RT rows x 64 k from pre-swizzled global (row stride 2048B) into LDS
template<int RT>
__device__ __forceinline__ void stage_tile(const char* g, char* l, int kb, int tid) {
    #pragma unroll
    for (int i = 0; i < RT / 32; ++i) {
        const int L = i * 4096 + tid * 16;
        gload16(g + (size_t)(L >> 7) * 2048 + (size_t)kb * 128 + (L & 127), l + L);
    }
}

// ---------------------------------------------------------------- 64x128 GEMM core
// 3-deep pipeline: stage(k+2) in flight; vmcnt(12)/(6)/(0) ladder.
// sA: 3 x 8KB, sB: 3 x 16KB (72KB).
__device__ __forceinline__ void mm128(
    int tid, char* sA, char* sB,
    const char* A, const char* B,
    f32x4 (&acc)[2][4])
{
    const int lane = tid & 63, w = tid >> 6;
    const int l15 = lane & 15, lg = lane >> 4;
    const int wr = w >> 1, wc = w & 1;
    int aoff[2][2], boff[4][2];
    #pragma unroll
    for (int fr = 0; fr < 2; ++fr)
        #pragma unroll
        for (int kk = 0; kk < 2; ++kk)
            aoff[fr][kk] = FRAGOFF(wr * 32 + fr * 16 + l15, kk * 4 + lg);
    #pragma unroll
    for (int fc = 0; fc < 4; ++fc)
        #pragma unroll
        for (int kk = 0; kk < 2; ++kk)
            boff[fc][kk] = FRAGOFF(wc * 64 + fc * 16 + l15, kk * 4 + lg);

    stage_tile<64>(A, sA, 0, tid);
    stage_tile<128>(B, sB, 0, tid);
    stage_tile<64>(A, sA + 8192, 1, tid);
    stage_tile<128>(B, sB + 16384, 1, tid);
    for (int kb = 0; kb < 16; ++kb) {
        const int kn = kb + 2;
        if (kn < 16) {
            const int bo = kn % 3;
            stage_tile<64>(A, sA + bo * 8192, kn, tid);
            stage_tile<128>(B, sB + bo * 16384, kn, tid);
            asm volatile("s_waitcnt vmcnt(12)" ::: "memory");
        } else if (kb + 1 < 16) {
            asm volatile("s_waitcnt vmcnt(6)" ::: "memory");
        } else {
            asm volatile("s_waitcnt vmcnt(0)" ::: "memory");
        }
        __builtin_amdgcn_s_barrier();
        __builtin_amdgcn_sched_barrier(0);
        const int bc = kb % 3;
        char* Ab = sA + bc * 8192;
        char* Bb = sB + bc * 16384;
        bf16x8 af[2][2], bv[4][2];
        #pragma unroll
        for (int fr = 0; fr < 2; ++fr)
            #pragma unroll
            for (int kk = 0; kk < 2; ++kk)
                af[fr][kk] = *reinterpret_cast<const bf16x8*>(Ab + aoff[fr][kk]);
        #pragma unroll
        for (int fc = 0; fc < 4; ++fc)
            #pragma unroll
            for (int kk = 0; kk < 2; ++kk)
                bv[fc][kk] = *reinterpret_cast<const bf16x8*>(Bb + boff[fc][kk]);
        __builtin_amdgcn_s_setprio(1);
        #pragma unroll
        for (int kk = 0; kk < 2; ++kk)
            #pragma unroll
            for (int fr = 0; fr < 2; ++fr)
                #pragma unroll
                for (int fc = 0; fc < 4; ++fc)
                    acc[fr][fc] = __builtin_amdgcn_mfma_f32_16x16x32_bf16(
                        af[fr][kk], bv[fc][kk], acc[fr][fc], 0, 0, 0);
        __builtin_amdgcn_s_setprio(0);
        __builtin_amdgcn_s_barrier();
        __builtin_amdgcn_sched_barrier(0);
    }
}

// ---------------------------------------------------------------- 32x64 1-seg 3-gate core
// 2-deep (proven). sA: 2 x 4KB, sB: 2 x 24KB (56KB).
__device__ __forceinline__ void mm32g1(
    int tid, char* sA, char* sB,
    const char* A, const char* Bg,
    f32x4 (&aR)[2], f32x4 (&aZ)[2], f32x4 (&aN)[2])
{
    const int lane = tid & 63, w = tid >> 6;
    const int l15 = lane & 15, lg = lane >> 4;
    const int wr = w >> 1, wc = w & 1;
    int aoff[2], boff[2][2];
    #pragma unroll
    for (int kk = 0; kk < 2; ++kk)
        aoff[kk] = FRAGOFF(wr * 16 + l15, kk * 4 + lg);
    #pragma unroll
    for (int fc = 0; fc < 2; ++fc)
        #pragma unroll
        for (int kk = 0; kk < 2; ++kk)
            boff[fc][kk] = FRAGOFF(wc * 32 + fc * 16 + l15, kk * 4 + lg);

    auto stg = [&](int buf, int kb) {
        stage_tile<32>(A, sA + buf * 4096, kb, tid);
        #pragma unroll
        for (int g = 0; g < 3; ++g)
            stage_tile<64>(Bg + (size_t)g * 2097152, sB + buf * 24576 + g * 8192, kb, tid);
    };
    stg(0, 0);
    for (int kb = 0; kb < 16; ++kb) {
        if (kb + 1 < 16) {
            stg((kb + 1) & 1, kb + 1);
            asm volatile("s_waitcnt vmcnt(7)" ::: "memory");
        } else {
            asm volatile("s_waitcnt vmcnt(0)" ::: "memory");
        }
        __builtin_amdgcn_s_barrier();
        __builtin_amdgcn_sched_barrier(0);
        char* Ab = sA + (kb & 1) * 4096;
        char* Bb = sB + (kb & 1) * 24576;
        bf16x8 af[2];
        #pragma unroll
        for (int kk = 0; kk < 2; ++kk)
            af[kk] = *reinterpret_cast<const bf16x8*>(Ab + aoff[kk]);
        bf16x8 bvr[2][2], bvz[2][2], bvn[2][2];
        #pragma unroll
        for (int fc = 0; fc < 2; ++fc)
            #pragma unroll
            for (int kk = 0; kk < 2; ++kk) {
                bvr[fc][kk] = *reinterpret_cast<const bf16x8*>(Bb + boff[fc][kk]);
                bvz[fc][kk] = *reinterpret_cast<const bf16x8*>(Bb + 8192 + boff[fc][kk]);
                bvn[fc][kk] = *reinterpret_cast<const bf16x8*>(Bb + 16384 + boff[fc][kk]);
            }
        __builtin_amdgcn_s_setprio(1);
        #pragma unroll
        for (int kk = 0; kk < 2; ++kk)
            #pragma unroll
            for (int fc = 0; fc < 2; ++fc) {
                aR[fc] = __builtin_amdgcn_mfma_f32_16x16x32_bf16(af[kk], bvr[fc][kk], aR[fc], 0, 0, 0);
                aZ[fc] = __builtin_amdgcn_mfma_f32_16x16x32_bf16(af[kk], bvz[fc][kk], aZ[fc], 0, 0, 0);
                aN[fc] = __builtin_amdgcn_mfma_f32_16x16x32_bf16(af[kk], bvn[fc][kk], aN[fc], 0, 0, 0);
            }
        __builtin_amdgcn_s_setprio(0);
        __builtin_amdgcn_s_barrier();
        __builtin_amdgcn_sched_barrier(0);
    }
}

// ---------------------------------------------------------------- shared bodies
__device__ __forceinline__ void do_xq(int slice, int i, int tid, char* sA, char* sB,
    const char* cbfB, const char* Wb, const float* act, const float* qW, float* out)
{
    const int lane = tid & 63, w = tid >> 6;
    const int l15 = lane & 15, lg = lane >> 4;
    const int wr = w >> 1, wc = w & 1;
    const int row0 = (i >> 4) * 64, col0 = (i & 15) * 128;
    const size_t grow0 = (size_t)slice * NB + row0;
    f32x4 acc[2][4] = {};
    mm128(tid, sA, sB, cbfB + grow0 * 2048, Wb + (size_t)(R_QWC + col0) * 2048, acc);
    #pragma unroll
    for (int fc = 0; fc < 4; ++fc) {
        const int gc = col0 + wc * 64 + fc * 16 + l15;
        const float* wp = qW + (size_t)gc * 2056 + 2048;
        float4 x0 = LD4(wp), x1 = LD4(wp + 4);
        #pragma unroll
        for (int fr = 0; fr < 2; ++fr)
            #pragma unroll
            for (int j = 0; j < 4; ++j) {
                const size_t n = grow0 + wr * 32 + fr * 16 + lg * 4 + j;
                const float* ar = act + n * 8;
                float4 a0 = LD4(ar), a1 = LD4(ar + 4);
                float dot = a0.x * x0.x + a0.y * x0.y + a0.z * x0.z + a0.w * x0.w
                          + a1.x * x1.x + a1.y * x1.y + a1.z * x1.z + a1.w * x1.w;
                out[OFF_Q + n * TWOH + gc] = acc[fr][fc][j] + dot;
            }
    }
}

__device__ __forceinline__ void do_gf(int slice, int i, int tid, char* sA, char* sB,
    const char* cbfB, const char* Wb, __bf16* Gfb)
{
    const int lane = tid & 63, w = tid >> 6;
    const int l15 = lane & 15, lg = lane >> 4;
    const int wr = w >> 1, wc = w & 1;
    const int row0 = (i / 24) * 64, col0 = (i % 24) * 128;
    f32x4 acc[2][4] = {};
    mm128(tid, sA, sB, cbfB + ((size_t)slice * NB + row0) * 2048,
          Wb + (size_t)(R_FWIH + col0) * 2048, acc);
    __bf16* gdst = Gfb + (size_t)(slice & 7) * NB * THREEH;
    #pragma unroll
    for (int fc = 0; fc < 4; ++fc) {
        const int gc = col0 + wc * 64 + fc * 16 + l15;
        #pragma unroll
        for (int fr = 0; fr < 2; ++fr)
            #pragma unroll
            for (int j = 0; j < 4; ++j) {
                const int n = row0 + wr * 32 + fr * 16 + lg * 4 + j;
                gdst[(size_t)n * THREEH + gc] = (__bf16)acc[fr][fc][j];
            }
    }
}

__device__ __forceinline__ void do_pq(int tt, int i, int tid, char* sA, char* sB,
    const __bf16* qmu_t, const char* Wb, const float* masks, const float* act,
    const float* pW, const float* pb, float* out)
{
    const int lane = tid & 63, w = tid >> 6;
    const int l15 = lane & 15, lg = lane >> 4;
    const int wr = w >> 1, wc = w & 1;
    const int row0 = (i >> 4) * 64, col0 = (i & 15) * 128;
    f32x4 acc[2][4] = {};
    mm128(tid, sA, sB, (const char*)qmu_t + (size_t)row0 * 2048,
          Wb + (size_t)(R_PWQ + col0) * 2048, acc);
    const float* mrow = masks + (size_t)tt * NB;
    float* ob = out + (size_t)tt * NB * TWOH;
    #pragma unroll
    for (int fc = 0; fc < 4; ++fc) {
        const int gc = col0 + wc * 64 + fc * 16 + l15;
        const float* wp = pW + (size_t)gc * 2056 + 2048;
        float4 x0 = LD4(wp), x1 = LD4(wp + 4);
        const float bb = pb[gc];
        #pragma unroll
        for (int fr = 0; fr < 2; ++fr)
            #pragma unroll
            for (int j = 0; j < 4; ++j) {
                const int n = row0 + wr * 32 + fr * 16 + lg * 4 + j;
                const float* ar = act + ((size_t)tt * NB + n) * 8;
                float4 a0 = LD4(ar), a1 = LD4(ar + 4);
                float dot = a0.x * x0.x + a0.y * x0.y + a0.z * x0.z + a0.w * x0.w
                          + a1.x * x1.x + a1.y * x1.y + a1.z * x1.z + a1.w * x1.w;
                ob[(size_t)n * TWOH + gc] = acc[fr][fc][j] + mrow[n] * dot + bb;
            }
    }
}

// ---------------------------------------------------------------- prepass kernels
__global__ __launch_bounds__(256) void wcvt_k(
    const float* __restrict__ pW, const float* __restrict__ qW,
    const float* __restrict__ fWih, const float* __restrict__ fWhh,
    const float* __restrict__ hWih, const float* __restrict__ hWhh,
    __bf16* __restrict__ Wbf)
{
    const long i = (long)blockIdx.x * 256 + threadIdx.x;
    const int row = (int)(i >> 7);
    const int G   = (int)i & 127;
    const float* src; int stride; int koff = 0; int r;
    if (row < 2048)       { src = pW;   stride = 2056; koff = 0;    r = row; }
    else if (row < 4096)  { src = pW;   stride = 2056; koff = 1024; r = row - 2048; }
    else if (row < 6144)  { src = qW;   stride = 2056; koff = 0;    r = row - 4096; }
    else if (row < 8192)  { src = qW;   stride = 2056; koff = 1024; r = row - 6144; }
    else if (row < 11264) { src = fWih; stride = 1024; r = row - 8192; }
    else if (row < 14336) { src = fWhh; stride = 1024; r = row - 11264; }
    else if (row < 17408) { src = hWih; stride = 1024; r = row - 14336; }
    else                  { src = hWhh; stride = 1024; r = row - 17408; }
    const float* p = src + (long)r * stride + koff + G * 8;
    float4 a = LD4(p), b = LD4(p + 4);
    bf16x8 v;
    v[0] = (__bf16)a.x; v[1] = (__bf16)a.y; v[2] = (__bf16)a.z; v[3] = (__bf16)a.w;
    v[4] = (__bf16)b.x; v[5] = (__bf16)b.y; v[6] = (__bf16)b.z; v[7] = (__bf16)b.w;
    *reinterpret_cast<bf16x8*>(Wbf + (size_t)row * 1024 + ((G ^ (row & 7)) << 3)) = v;
}

__global__ __launch_bounds__(256) void ccvt_k(const float* __restrict__ c,
                                              __bf16* __restrict__ cbf) {
    const long i = (long)blockIdx.x * 256 + threadIdx.x;
    const int row = (int)(i >> 7);
    const int G   = (int)i & 127;
    const float* p = c + (size_t)row * 1024 + G * 8;
    float4 a = LD4(p), b = LD4(p + 4);
    bf16x8 v;
    v[0] = (__bf16)a.x; v[1] = (__bf16)a.y; v[2] = (__bf16)a.z; v[3] = (__bf16)a.w;
    v[4] = (__bf16)b.x; v[5] = (__bf16)b.y; v[6] = (__bf16)b.z; v[7] = (__bf16)b.w;
    *reinterpret_cast<bf16x8*>(cbf + (size_t)row * 1024 + ((G ^ (row & 7)) << 3)) = v;
}

__global__ __launch_bounds__(256) void init2_k(
    const float* __restrict__ hxs, const float* __restrict__ masks,
    float* __restrict__ fst0, float* __restrict__ hst0,
    __bf16* __restrict__ fbm0, __bf16* __restrict__ hbm0, __bf16* __restrict__ qmub0)
{
    const int idx = blockIdx.x * 256 + threadIdx.x;
    const int arr = idx >> 15;
    const int g   = idx & 32767;
    const int n   = g >> 7;
    const int G   = g & 127;
    const float m0 = masks[n];
    const float* p = hxs + (size_t)n * THREEH + arr * 1024 + G * 8;
    float4 a = LD4(p), b = LD4(p + 4);
    __bf16* dstB = arr == 0 ? fbm0 : (arr == 1 ? hbm0 : qmub0);
    bf16x8 v;
    v[0] = (__bf16)(a.x * m0); v[1] = (__bf16)(a.y * m0);
    v[2] = (__bf16)(a.z * m0); v[3] = (__bf16)(a.w * m0);
    v[4] = (__bf16)(b.x * m0); v[5] = (__bf16)(b.y * m0);
    v[6] = (__bf16)(b.z * m0); v[7] = (__bf16)(b.w * m0);
    *reinterpret_cast<bf16x8*>(dstB + (size_t)n * 1024 + ((G ^ (n & 7)) << 3)) = v;
    if (arr < 2) {
        float* dstF = arr == 0 ? fst0 : hst0;
        *reinterpret_cast<float4*>(dstF + (size_t)n * 1024 + G * 8) = a;
        *reinterpret_cast<float4*>(dstF + (size_t)n * 1024 + G * 8 + 4) = b;
    }
}

// slices 0..LA-1 of xq and Gf, plus Pq(0)
__global__ __launch_bounds__(256) void pre_k(
    const char* __restrict__ cbfB, const char* __restrict__ Wb,
    const float* __restrict__ act, const float* __restrict__ qW,
    const __bf16* __restrict__ qmb0, const float* __restrict__ masks,
    const float* __restrict__ pW, const float* __restrict__ pb,
    __bf16* __restrict__ Gfb, float* __restrict__ out)
{
    __shared__ char smem[73728];
    if (blockIdx.x < LA * 160) {
        const int s = blockIdx.x / 160;
        const int i = blockIdx.x % 160;
        if (i < 64) do_xq(s, i, threadIdx.x, smem, smem + 24576, cbfB, Wb, act, qW, out);
        else        do_gf(s, i - 64, threadIdx.x, smem, smem + 24576, cbfB, Wb, Gfb);
    } else {
        do_pq(0, blockIdx.x - LA * 160, threadIdx.x, smem, smem + 24576,
              qmb0, Wb, masks, act, pW, pb, out);
    }
}

// ---------------------------------------------------------------- per-step K1 (352)
// [0,64) Pfinal | [64,128) Q | [128,224) h@hWhh->Shh | [224,352) f-GRU
__global__ __launch_bounds__(256) void k1_k(
    int t,
    const __bf16* __restrict__ hbm, const __bf16* __restrict__ fbm,
    __bf16* __restrict__ qmubN,
    const float* __restrict__ masks, const float* __restrict__ act,
    const float* __restrict__ qb, const float* __restrict__ qW,
    const char* __restrict__ Wb,
    __bf16* __restrict__ pmub, float* __restrict__ Shh,
    const __bf16* __restrict__ Gfb,
    const float* __restrict__ fbih, const float* __restrict__ fbhh,
    const float* __restrict__ fstF, float* __restrict__ fstN, __bf16* __restrict__ fbmN,
    float* __restrict__ out)
{
    __shared__ char smem[73728];
    char* sA = smem;
    char* sB = smem + 24576;
    const int tid = threadIdx.x;
    const int lane = tid & 63, w = tid >> 6;
    const int l15 = lane & 15, lg = lane >> 4;
    const int wr = w >> 1, wc = w & 1;
    const float* mrow = masks + (size_t)t * NB;
    const float* mn   = masks + (size_t)(t + 1 < T ? t + 1 : t) * NB;
    int b = blockIdx.x;

    if (b < 64) {           // ---- Pfinal: out[t] += h@pWh
        const int row0 = (b >> 4) * 64, col0 = (b & 15) * 128;
        f32x4 acc[2][4] = {};
        mm128(tid, sA, sB, (const char*)hbm + (size_t)row0 * 2048,
              Wb + (size_t)(R_PWH + col0) * 2048, acc);
        float* ob = out + (size_t)t * NB * TWOH;
        #pragma unroll
        for (int fc = 0; fc < 4; ++fc) {
            const int gc = col0 + wc * 64 + fc * 16 + l15;
            #pragma unroll
            for (int fr = 0; fr < 2; ++fr)
                #pragma unroll
                for (int j = 0; j < 4; ++j) {
                    const int n = row0 + wr * 32 + fr * 16 + lg * 4 + j;
                    const float v = ob[(size_t)n * TWOH + gc] + acc[fr][fc][j];
                    ob[(size_t)n * TWOH + gc] = v;
                    if (gc < 1024) st_bf_swz(pmub, n, gc, v);
                }
        }
    } else if (b < 128) {   // ---- Q
        b -= 64;
        const int row0 = (b >> 4) * 64, col0 = (b & 15) * 128;
        f32x4 acc[2][4] = {};
        mm128(tid, sA, sB, (const char*)fbm + (size_t)row0 * 2048,
              Wb + (size_t)(R_QWF + col0) * 2048, acc);
        float* ob = out + OFF_Q + (size_t)t * NB * TWOH;
        #pragma unroll
        for (int fc = 0; fc < 4; ++fc) {
            const int gc = col0 + wc * 64 + fc * 16 + l15;
            const float bb = qb[gc];
            #pragma unroll
            for (int fr = 0; fr < 2; ++fr)
                #pragma unroll
                for (int j = 0; j < 4; ++j) {
                    const int n = row0 + wr * 32 + fr * 16 + lg * 4 + j;
                    const float xq = ob[(size_t)n * TWOH + gc];
                    float v = acc[fr][fc][j] + mrow[n] * xq + bb;
                    ob[(size_t)n * TWOH + gc] = v;
                    if (gc < 1024) st_bf_swz(qmubN, n, gc, v * mn[n]);
                }
        }
    } else if (b < 224) {   // ---- h@hWhh -> Shh
        const int i = b - 128;
        const int row0 = (i / 24) * 64, col0 = (i % 24) * 128;
        f32x4 acc[2][4] = {};
        mm128(tid, sA, sB, (const char*)hbm + (size_t)row0 * 2048,
              Wb + (size_t)(R_HWHH + col0) * 2048, acc);
        #pragma unroll
        for (int fc = 0; fc < 4; ++fc) {
            const int gc = col0 + wc * 64 + fc * 16 + l15;
            #pragma unroll
            for (int fr = 0; fr < 2; ++fr)
                #pragma unroll
                for (int j = 0; j < 4; ++j) {
                    const int n = row0 + wr * 32 + fr * 16 + lg * 4 + j;
                    Shh[(size_t)n * THREEH + gc] = acc[fr][fc][j];
                }
        }
    } else {                // ---- f-GRU: f@fWhh + Gf ring + combine
        const int i = b - 224;
        const int row0 = (i >> 4) * 32, col0 = (i & 15) * 64;
        f32x4 aR[2] = {}, aZ[2] = {}, aN[2] = {};
        mm32g1(tid, sA, sB, (const char*)fbm + (size_t)row0 * 2048,
               Wb + (size_t)(R_FWHH + col0) * 2048, aR, aZ, aN);
        const __bf16* gsl = Gfb + (size_t)(t & 7) * NB * THREEH;
        #pragma unroll
        for (int fc = 0; fc < 2; ++fc) {
            const int col = col0 + wc * 32 + fc * 16 + l15;
            const float br  = fbih[col] + fbhh[col];
            const float bz  = fbih[col + 1024] + fbhh[col + 1024];
            const float bni = fbih[col + 2048], bnh = fbhh[col + 2048];
            #pragma unroll
            for (int j = 0; j < 4; ++j) {
                const int n = row0 + wr * 16 + lg * 4 + j;
                const float gfr = (float)gsl[(size_t)n * THREEH + col];
                const float gfz = (float)gsl[(size_t)n * THREEH + col + 1024];
                const float gfn = (float)gsl[(size_t)n * THREEH + col + 2048];
                const float rg = sigf(gfr + aR[fc][j] + br);
                const float zg = sigf(gfz + aZ[fc][j] + bz);
                const float ng = tanhf(gfn + bni + rg * (aN[fc][j] + bnh));
                const float fm = fstF[(size_t)n * 1024 + col] * mrow[n];
                const float o = (1.f - zg) * ng + zg * fm;
                fstN[(size_t)n * 1024 + col] = o;
                st_bf_swz(fbmN, n, col, o * mn[n]);
            }
        }
    }
}

// ---------------------------------------------------------------- per-step K2 (352)
// [0,128) h-GRU | [128,192) Pq(t+1) | [192,256) xq(t+LA) | [256,352) Gf(t+LA)
__global__ __launch_bounds__(256) void k2_k(
    int t,
    const __bf16* __restrict__ pmub, const __bf16* __restrict__ qmubN,
    const char* __restrict__ cbfB,
    const float* __restrict__ Shh,
    const float* __restrict__ hstF, float* __restrict__ hstN, __bf16* __restrict__ hbmN,
    const char* __restrict__ Wb,
    const float* __restrict__ hbih, const float* __restrict__ hbhh,
    const float* __restrict__ masks, const float* __restrict__ act,
    const float* __restrict__ pW, const float* __restrict__ pb,
    const float* __restrict__ qW,
    __bf16* __restrict__ Gfb, float* __restrict__ out)
{
    __shared__ char smem[73728];
    char* sA = smem;
    char* sB = smem + 24576;
    const int tid = threadIdx.x;
    const int lane = tid & 63, w = tid >> 6;
    const int l15 = lane & 15, lg = lane >> 4;
    const int wr = w >> 1, wc = w & 1;
    const float* mrow = masks + (size_t)t * NB;
    const float* mn   = masks + (size_t)(t + 1 < T ? t + 1 : t) * NB;
    const int b = blockIdx.x;

    if (b < 128) {          // ---- h-GRU: pmu@hWih + Shh + combine
        const int row0 = (b >> 4) * 32, col0 = (b & 15) * 64;
        f32x4 aR[2] = {}, aZ[2] = {}, aN[2] = {};
        mm32g1(tid, sA, sB, (const char*)pmub + (size_t)row0 * 2048,
               Wb + (size_t)(R_HWIH + col0) * 2048, aR, aZ, aN);
        #pragma unroll
        for (int fc = 0; fc < 2; ++fc) {
            const int col = col0 + wc * 32 + fc * 16 + l15;
            const float bri = hbih[col],        brh = hbhh[col];
            const float bzi = hbih[col + 1024], bzh = hbhh[col + 1024];
            const float bni = hbih[col + 2048], bnh = hbhh[col + 2048];
            #pragma unroll
            for (int j = 0; j < 4; ++j) {
                const int n = row0 + wr * 16 + lg * 4 + j;
                const float ghr = Shh[(size_t)n * THREEH + col];
                const float ghz = Shh[(size_t)n * THREEH + col + 1024];
                const float ghn = Shh[(size_t)n * THREEH + col + 2048];
                const float rg = sigf(aR[fc][j] + bri + ghr + brh);
                const float zg = sigf(aZ[fc][j] + bzi + ghz + bzh);
                const float ng = tanhf(aN[fc][j] + bni + rg * (ghn + bnh));
                const float hm = hstF[(size_t)n * 1024 + col] * mrow[n];
                const float o = (1.f - zg) * ng + zg * hm;
                hstN[(size_t)n * 1024 + col] = o;
                st_bf_swz(hbmN, n, col, o * mn[n]);
            }
        }
    } else if (b < 192) {   // ---- Pq partial for step t+1
        if (t + 1 < T)
            do_pq(t + 1, b - 128, tid, sA, sB, qmubN, Wb, masks, act, pW, pb, out);
    } else if (b < 256) {   // ---- xq filler (slice t+LA)
        if (t + LA < T)
            do_xq(t + LA, b - 192, tid, sA, sB, cbfB, Wb, act, qW, out);
    } else {                // ---- Gf filler (slice t+LA)
        if (t + LA < T)
            do_gf(t + LA, b - 256, tid, sA, sB, cbfB, Wb, Gfb);
    }
}

// ---------------------------------------------------------------- final hxs
__global__ __launch_bounds__(256) void write_hxs_k(const float* __restrict__ fS,
                                                   const float* __restrict__ hS,
                                                   float* out) {
    const int i = blockIdx.x * 256 + threadIdx.x;
    const int n = i / THREEH;
    const int j = i - n * THREEH;
    float v;
    if (j < H)          v = fS[(size_t)n * H + j];
    else if (j < TWOH)  v = hS[(size_t)n * H + (j - H)];
    else                v = out[OFF_Q + ((size_t)(T - 1) * NB + n) * TWOH + (j - TWOH)];
    out[OFF_HX + i] = v;
}

// ---------------------------------------------------------------- launcher
extern "C" void kernel_launch(void* const* d_in, const int* in_sizes, int n_in,
                              void* d_out, int out_size, void* d_ws, size_t ws_size,
                              hipStream_t stream) {
    (void)in_sizes; (void)n_in; (void)out_size; (void)ws_size;

    const float* c     = (const float*)d_in[0];
    const float* hxs   = (const float*)d_in[1];
    const float* masks = (const float*)d_in[2];
    const float* act   = (const float*)d_in[3];
    const float* hWih  = (const float*)d_in[4];
    const float* hWhh  = (const float*)d_in[5];
    const float* hbih  = (const float*)d_in[6];
    const float* hbhh  = (const float*)d_in[7];
    const float* fWih  = (const float*)d_in[8];
    const float* fWhh  = (const float*)d_in[9];
    const float* fbih  = (const float*)d_in[10];
    const float* fbhh  = (const float*)d_in[11];
    const float* pW    = (const float*)d_in[12];
    const float* pb    = (const float*)d_in[13];
    const float* qW    = (const float*)d_in[14];
    const float* qb    = (const float*)d_in[15];

    float* out = (float*)d_out;
    char*  wsb = (char*)d_ws;

    __bf16* Wbf  = (__bf16*)(wsb);                               // 41.94 MB
    __bf16* cbf  = (__bf16*)(wsb + 41943040LL);                  // 33.55 MB
    float*  fst[2] = { (float*)(wsb + 75497472LL), (float*)(wsb + 76546048LL) };
    float*  hst[2] = { (float*)(wsb + 77594624LL), (float*)(wsb + 78643200LL) };
    __bf16* fbm[2] = { (__bf16*)(wsb + 79691776LL), (__bf16*)(wsb + 80216064LL) };
    __bf16* hbm[2] = { (__bf16*)(wsb + 80740352LL), (__bf16*)(wsb + 81264640LL) };
    __bf16* qmb[2] = { (__bf16*)(wsb + 81788928LL), (__bf16*)(wsb + 82313216LL) };
    __bf16* pmub   = (__bf16*)(wsb + 82837504LL);                // 0.52 MB
    float*  Shh    = (float*)(wsb + 83361792LL);                 // 3.15 MB
    __bf16* Gfb    = (__bf16*)(wsb + 86507520LL);                // 8 x 1.57 MB -> ~99.1 MB
    const char* Wb   = (const char*)Wbf;
    const char* cbfB = (const char*)cbf;

    wcvt_k <<<dim3(10240), dim3(256), 0, stream>>>(pW, qW, fWih, fWhh, hWih, hWhh, Wbf);
    ccvt_k <<<dim3(8192),  dim3(256), 0, stream>>>(c, cbf);
    init2_k<<<dim3(384),   dim3(256), 0, stream>>>(hxs, masks, fst[0], hst[0],
                                                   fbm[0], hbm[0], qmb[0]);
    pre_k  <<<dim3(LA * 160 + 64), dim3(256), 0, stream>>>(
        cbfB, Wb, act, qW, qmb[0], masks, pW, pb, Gfb, out);

    for (int t = 0; t < T; ++t) {
        const int cur = t & 1, nxt = cur ^ 1;
        k1_k<<<dim3(352), dim3(256), 0, stream>>>(
            t, hbm[cur], fbm[cur], qmb[nxt],
            masks, act, qb, qW, Wb, pmub, Shh, Gfb,
            fbih, fbhh, fst[cur], fst[nxt], fbm[nxt], out);
        k2_k<<<dim3(352), dim3(256), 0, stream>>>(
            t, pmub, qmb[nxt], cbfB, Shh,
            hst[cur], hst[nxt], hbm[nxt],
            Wb, hbih, hbhh, masks, act, pW, pb, qW, Gfb, out);
    }

    write_hxs_k<<<dim3(3072), dim3(256), 0, stream>>>(fst[0], hst[0], out);
}